// Round 3
// baseline (740.650 us; speedup 1.0000x reference)
//
#include <hip/hip_runtime.h>

typedef __attribute__((ext_vector_type(8))) short short8;
typedef __attribute__((ext_vector_type(4))) float f32x4;
typedef unsigned long long ull;

static __device__ __forceinline__ unsigned short f2bf(float f) {
    union { float f; unsigned int u; } v; v.f = f;
    unsigned int r = v.u + 0x7fffu + ((v.u >> 16) & 1u);  // RNE
    return (unsigned short)(r >> 16);
}

static __device__ __forceinline__ short8 pack8(float4 a, float4 b) {
    short8 r;
    r[0] = (short)f2bf(a.x); r[1] = (short)f2bf(a.y);
    r[2] = (short)f2bf(a.z); r[3] = (short)f2bf(a.w);
    r[4] = (short)f2bf(b.x); r[5] = (short)f2bf(b.y);
    r[6] = (short)f2bf(b.z); r[7] = (short)f2bf(b.w);
    return r;
}

__global__ void k_zero(uint4* p, int n16) {
    int i = blockIdx.x * blockDim.x + threadIdx.x;
    if (i < n16) p[i] = uint4{0u, 0u, 0u, 0u};
}

// W1,W2 (f32 [128][256]) -> 4 bf16 [128][128] row-major (row j = output col j)
__global__ void k_convw(const float* __restrict__ W1, const float* __restrict__ W2,
                        unsigned short* W1a, unsigned short* W1b,
                        unsigned short* W2a, unsigned short* W2b) {
    int j = blockIdx.x;
    int k = threadIdx.x;
    float w1 = W1[j * 256 + k], w2 = W2[j * 256 + k];
    if (k < 128) { W1a[j * 128 + k] = f2bf(w1); W2a[j * 128 + k] = f2bf(w2); }
    else         { W1b[j * 128 + k - 128] = f2bf(w1); W2b[j * 128 + k - 128] = f2bf(w2); }
}

__global__ void k_mark(const int* __restrict__ ids, int* __restrict__ cum, int n) {
    int i = blockIdx.x * blockDim.x + threadIdx.x;
    if (i < n) cum[ids[i]] = 1;
}

// 2-level scan: per-block inclusive scan of 1024 ints + block sums
__global__ __launch_bounds__(256) void k_scan1(int* __restrict__ cum, int* __restrict__ bsum, int G) {
    __shared__ int ws[4];
    int tid = threadIdx.x;
    int base = blockIdx.x * 1024 + tid * 4;
    int a0 = 0, a1 = 0, a2 = 0, a3 = 0;
    if (base + 0 < G) a0 = cum[base + 0];
    if (base + 1 < G) a1 = cum[base + 1];
    if (base + 2 < G) a2 = cum[base + 2];
    if (base + 3 < G) a3 = cum[base + 3];
    int s = a0 + a1 + a2 + a3;
    int lane = tid & 63;
    int v = s;
#pragma unroll
    for (int off = 1; off < 64; off <<= 1) {
        int u = __shfl_up(v, off, 64);
        if (lane >= off) v += u;
    }
    if (lane == 63) ws[tid >> 6] = v;
    __syncthreads();
    int wof = 0;
    for (int w = 0; w < (tid >> 6); ++w) wof += ws[w];
    int excl = wof + v - s;
    int r0 = excl + a0, r1 = r0 + a1, r2 = r1 + a2, r3 = r2 + a3;
    if (base + 0 < G) cum[base + 0] = r0;
    if (base + 1 < G) cum[base + 1] = r1;
    if (base + 2 < G) cum[base + 2] = r2;
    if (base + 3 < G) cum[base + 3] = r3;
    if (tid == 255) bsum[blockIdx.x] = excl + s;
}

__global__ void k_scan2(int* __restrict__ bsum, int nb) {
    int t = threadIdx.x;  // 64 threads, nb <= 64
    int v = (t < nb) ? bsum[t] : 0;
#pragma unroll
    for (int off = 1; off < 64; off <<= 1) {
        int u = __shfl_up(v, off, 64);
        if (t >= off) v += u;
    }
    if (t < nb) bsum[t] = v;
}

__global__ void k_gid(const int* __restrict__ ids, const int* __restrict__ cum,
                      const int* __restrict__ bsum, int* __restrict__ gid,
                      int* __restrict__ gstart, int* __restrict__ ngr, int n) {
    int i = blockIdx.x * blockDim.x + threadIdx.x;
    if (i >= n) return;
    int v = ids[i];
    int blk = v >> 10;
    int g = cum[v] + (blk ? bsum[blk - 1] : 0) - 1;
    gid[i] = g;
    if (i == 0 || ids[i - 1] != v) gstart[g] = i;
    if (i == n - 1) { gstart[g + 1] = n; *ngr = g + 1; }
}

// E1 = emb @ W1b^T. Register-streaming: no LDS, no barriers, 2-deep prefetch.
__global__ __launch_bounds__(256, 2) void k_egemm(
    const float* __restrict__ emb, const unsigned short* __restrict__ W1b,
    float* __restrict__ E1, int G) {
    int tid = threadIdx.x, lane = tid & 63, wid = tid >> 6;
    int p = lane & 15, q = lane >> 4;
    int wr = wid >> 1, wc = wid & 1;
    int nt = (G + 15) >> 4;
    int stride = gridDim.x * 2;
    int t0 = blockIdx.x * 2 + wr;

    short8 bfr[4][4];
#pragma unroll
    for (int t = 0; t < 4; ++t)
#pragma unroll
        for (int kk = 0; kk < 4; ++kk)
            bfr[t][kk] = *(const short8*)&W1b[(size_t)(wc * 64 + t * 16 + p) * 128 + kk * 32 + q * 8];

    if (t0 >= nt) return;
    float4 cur[8], nxt[8];
    {
        size_t rc = (size_t)min(t0 * 16 + p, G - 1) * 128;
#pragma unroll
        for (int kk = 0; kk < 4; ++kk) {
            cur[2 * kk]     = *(const float4*)(emb + rc + kk * 32 + q * 8);
            cur[2 * kk + 1] = *(const float4*)(emb + rc + kk * 32 + q * 8 + 4);
        }
    }
    for (;;) {
        int t1 = t0 + stride;
        bool more = (t1 < nt);
        if (more) {
            size_t rc = (size_t)min(t1 * 16 + p, G - 1) * 128;
#pragma unroll
            for (int kk = 0; kk < 4; ++kk) {
                nxt[2 * kk]     = *(const float4*)(emb + rc + kk * 32 + q * 8);
                nxt[2 * kk + 1] = *(const float4*)(emb + rc + kk * 32 + q * 8 + 4);
            }
        }
        short8 afr[4];
#pragma unroll
        for (int kk = 0; kk < 4; ++kk) afr[kk] = pack8(cur[2 * kk], cur[2 * kk + 1]);
        f32x4 acc[4];
#pragma unroll
        for (int t = 0; t < 4; ++t) acc[t] = f32x4{0.f, 0.f, 0.f, 0.f};
#pragma unroll
        for (int t = 0; t < 4; ++t)
#pragma unroll
            for (int kk = 0; kk < 4; ++kk)
                acc[t] = __builtin_amdgcn_mfma_f32_16x16x32_bf16(afr[kk], bfr[t][kk], acc[t], 0, 0, 0);
#pragma unroll
        for (int t = 0; t < 4; ++t) {
            int colb = wc * 64 + t * 16 + p;
#pragma unroll
            for (int rg = 0; rg < 4; ++rg) {
                int rr = t0 * 16 + q * 4 + rg;
                if (rr < G) E1[(size_t)rr * 128 + colb] = acc[t][rg];
            }
        }
        if (!more) break;
#pragma unroll
        for (int i = 0; i < 8; ++i) cur[i] = nxt[i];
        t0 = t1;
    }
}

// x_out = x @ W1a^T + E1[gid] + b1 ; fused in-register segmented sums -> segsum.
// Register-streaming: no LDS, no barriers; wc waves duplicate x loads (L1/L2-hot)
// and partition the segment-sum columns (wc=0: kk 0,1 ; wc=1: kk 2,3).
__global__ __launch_bounds__(256, 2) void k_xgemm(
    const float* __restrict__ x, const unsigned short* __restrict__ W1a,
    const int* __restrict__ gid, const float* __restrict__ E1,
    const float* __restrict__ b1, float* __restrict__ out,
    float* __restrict__ segsum, int N) {
    int tid = threadIdx.x, lane = tid & 63, wid = tid >> 6;
    int p = lane & 15, q = lane >> 4;
    int wr = wid >> 1, wc = wid & 1;
    int nt = (N + 15) >> 4;
    int stride = gridDim.x * 2;
    int t0 = blockIdx.x * 2 + wr;

    short8 bfr[4][4];
#pragma unroll
    for (int t = 0; t < 4; ++t)
#pragma unroll
        for (int kk = 0; kk < 4; ++kk)
            bfr[t][kk] = *(const short8*)&W1a[(size_t)(wc * 64 + t * 16 + p) * 128 + kk * 32 + q * 8];
    float b1v[4];
#pragma unroll
    for (int t = 0; t < 4; ++t) b1v[t] = b1[wc * 64 + t * 16 + p];

    if (t0 >= nt) return;
    float4 cur[8], nxt[8];
    {
        size_t rc = (size_t)min(t0 * 16 + p, N - 1) * 128;
#pragma unroll
        for (int kk = 0; kk < 4; ++kk) {
            cur[2 * kk]     = *(const float4*)(x + rc + kk * 32 + q * 8);
            cur[2 * kk + 1] = *(const float4*)(x + rc + kk * 32 + q * 8 + 4);
        }
    }
    for (;;) {
        int t1 = t0 + stride;
        bool more = (t1 < nt);
        if (more) {
            size_t rc = (size_t)min(t1 * 16 + p, N - 1) * 128;
#pragma unroll
            for (int kk = 0; kk < 4; ++kk) {
                nxt[2 * kk]     = *(const float4*)(x + rc + kk * 32 + q * 8);
                nxt[2 * kk + 1] = *(const float4*)(x + rc + kk * 32 + q * 8 + 4);
            }
        }
        int myrow = t0 * 16 + p;
        int rowc = myrow < N ? myrow : N - 1;
        int g = gid[rowc];

        // segment boundary prep (rows = p within the 16-row tile)
        int gpv = __shfl(g, lane > 0 ? lane - 1 : 0);
        int gnx = __shfl(g, lane < 63 ? lane + 1 : 63);
        bool is_start = (p == 0) || (gpv != g);
        bool is_end = (p == 15) || (gnx != g);
        ull smask = __ballot(is_start);
        ull below = smask & (~0ULL >> (63 - lane));
        int startlane = 63 - __builtin_clzll(below);
        bool has_before = (startlane & 15) != 0;
        int pbl = startlane > 0 ? startlane - 1 : 0;

        short8 afr[4];
#pragma unroll
        for (int kk = 0; kk < 4; ++kk) afr[kk] = pack8(cur[2 * kk], cur[2 * kk + 1]);

        // segmented inclusive scan over 16 row-lanes for this wave's column half
#pragma unroll
        for (int kx = 0; kx < 2; ++kx) {
            int kk = wc * 2 + kx;
            float4 va = cur[2 * kk], vb = cur[2 * kk + 1];
            float v[8] = {va.x, va.y, va.z, va.w, vb.x, vb.y, vb.z, vb.w};
            if (myrow >= N) {
#pragma unroll
                for (int j = 0; j < 8; ++j) v[j] = 0.f;
            }
#pragma unroll
            for (int j = 0; j < 8; ++j) { float u = __shfl_up(v[j], 1, 16); if (p >= 1) v[j] += u; }
#pragma unroll
            for (int j = 0; j < 8; ++j) { float u = __shfl_up(v[j], 2, 16); if (p >= 2) v[j] += u; }
#pragma unroll
            for (int j = 0; j < 8; ++j) { float u = __shfl_up(v[j], 4, 16); if (p >= 4) v[j] += u; }
#pragma unroll
            for (int j = 0; j < 8; ++j) { float u = __shfl_up(v[j], 8, 16); if (p >= 8) v[j] += u; }
#pragma unroll
            for (int j = 0; j < 8; ++j) {
                float pb = __shfl(v[j], pbl);
                if (is_end) {
                    float seg = v[j] - (has_before ? pb : 0.f);
                    atomicAdd(&segsum[(size_t)g * 128 + kk * 32 + q * 8 + j], seg);
                }
            }
        }

        f32x4 acc[4];
#pragma unroll
        for (int t = 0; t < 4; ++t) acc[t] = f32x4{0.f, 0.f, 0.f, 0.f};
#pragma unroll
        for (int t = 0; t < 4; ++t)
#pragma unroll
            for (int kk = 0; kk < 4; ++kk)
                acc[t] = __builtin_amdgcn_mfma_f32_16x16x32_bf16(afr[kk], bfr[t][kk], acc[t], 0, 0, 0);

        int g4[4];
#pragma unroll
        for (int rg = 0; rg < 4; ++rg) g4[rg] = __shfl(g, q * 4 + rg);
#pragma unroll
        for (int t = 0; t < 4; ++t) {
            int colb = wc * 64 + t * 16 + p;
#pragma unroll
            for (int rg = 0; rg < 4; ++rg) {
                int rr = t0 * 16 + q * 4 + rg;
                if (rr < N)
                    out[(size_t)rr * 128 + colb] = acc[t][rg] + E1[(size_t)g4[rg] * 128 + colb] + b1v[t];
            }
        }
        if (!more) break;
#pragma unroll
        for (int i = 0; i < 8; ++i) cur[i] = nxt[i];
        t0 = t1;
    }
}

// imputed_out = emb @ W2a^T + imp_second @ W2b^T + b2, mean computed in-register.
// One 16-row tile per wave-pair; register path only.
__global__ __launch_bounds__(256, 2) void k_igemm(
    const float* __restrict__ emb, const float* __restrict__ segsum,
    const unsigned short* __restrict__ W2a, const unsigned short* __restrict__ W2b,
    const float* __restrict__ b2, const int* __restrict__ gstart,
    const int* __restrict__ ngr, float* __restrict__ out2, int G) {
    int tid = threadIdx.x, lane = tid & 63, wid = tid >> 6;
    int p = lane & 15, q = lane >> 4;
    int wr = wid >> 1, wc = wid & 1;
    int nt = (G + 15) >> 4;
    int t0 = blockIdx.x * 2 + wr;
    if (t0 >= nt) return;
    int ng = *ngr;

    short8 bfrA[4][4], bfrB[4][4];
#pragma unroll
    for (int t = 0; t < 4; ++t)
#pragma unroll
        for (int kk = 0; kk < 4; ++kk) {
            bfrA[t][kk] = *(const short8*)&W2a[(size_t)(wc * 64 + t * 16 + p) * 128 + kk * 32 + q * 8];
            bfrB[t][kk] = *(const short8*)&W2b[(size_t)(wc * 64 + t * 16 + p) * 128 + kk * 32 + q * 8];
        }
    float b2v[4];
#pragma unroll
    for (int t = 0; t < 4; ++t) b2v[t] = b2[wc * 64 + t * 16 + p];

    int rowc = min(t0 * 16 + p, G - 1);
    bool written = rowc < ng - 1;
    int cnt = gstart[rowc + 1] - gstart[rowc];  // garbage if !written (unused)
    float inv = written ? 1.0f / (float)(cnt > 0 ? cnt : 1) : 0.f;

    float4 e[8], s[8];
    {
        size_t rc = (size_t)rowc * 128;
#pragma unroll
        for (int kk = 0; kk < 4; ++kk) {
            e[2 * kk]     = *(const float4*)(emb + rc + kk * 32 + q * 8);
            e[2 * kk + 1] = *(const float4*)(emb + rc + kk * 32 + q * 8 + 4);
            s[2 * kk]     = *(const float4*)(segsum + rc + kk * 32 + q * 8);
            s[2 * kk + 1] = *(const float4*)(segsum + rc + kk * 32 + q * 8 + 4);
        }
    }
    f32x4 acc[4];
#pragma unroll
    for (int t = 0; t < 4; ++t) acc[t] = f32x4{0.f, 0.f, 0.f, 0.f};
#pragma unroll
    for (int kk = 0; kk < 4; ++kk) {
        short8 ae = pack8(e[2 * kk], e[2 * kk + 1]);
        float4 m0, m1;
        float4 s0 = s[2 * kk], s1 = s[2 * kk + 1];
        float4 e0 = e[2 * kk], e1 = e[2 * kk + 1];
        m0.x = written ? s0.x * inv : e0.x; m0.y = written ? s0.y * inv : e0.y;
        m0.z = written ? s0.z * inv : e0.z; m0.w = written ? s0.w * inv : e0.w;
        m1.x = written ? s1.x * inv : e1.x; m1.y = written ? s1.y * inv : e1.y;
        m1.z = written ? s1.z * inv : e1.z; m1.w = written ? s1.w * inv : e1.w;
        short8 am = pack8(m0, m1);
#pragma unroll
        for (int t = 0; t < 4; ++t) {
            acc[t] = __builtin_amdgcn_mfma_f32_16x16x32_bf16(ae, bfrA[t][kk], acc[t], 0, 0, 0);
            acc[t] = __builtin_amdgcn_mfma_f32_16x16x32_bf16(am, bfrB[t][kk], acc[t], 0, 0, 0);
        }
    }
#pragma unroll
    for (int t = 0; t < 4; ++t) {
        int colb = wc * 64 + t * 16 + p;
#pragma unroll
        for (int rg = 0; rg < 4; ++rg) {
            int rr = t0 * 16 + q * 4 + rg;
            if (rr < G) out2[(size_t)rr * 128 + colb] = acc[t][rg] + b2v[t];
        }
    }
}

extern "C" void kernel_launch(void* const* d_in, const int* in_sizes, int n_in,
                              void* d_out, int out_size, void* d_ws, size_t ws_size,
                              hipStream_t stream) {
    const float* x   = (const float*)d_in[0];
    const float* emb = (const float*)d_in[1];
    const float* W1  = (const float*)d_in[2];
    const float* b1  = (const float*)d_in[3];
    const float* W2  = (const float*)d_in[4];
    const float* b2  = (const float*)d_in[5];
    const int*   ids = (const int*)d_in[6];
    const int H = 128;
    const int N = in_sizes[6];
    const int G = in_sizes[1] / H;

    float* out  = (float*)d_out;
    float* out2 = out + (size_t)N * H;
    float* E1   = out2;  // E1 scratch lives in imputed_out region (overwritten by k_igemm last)

    char* ws = (char*)d_ws;
    size_t off = 0;
    float* segsum = (float*)(ws + off); off += (size_t)G * H * 4;
    int*   cum    = (int*)(ws + off);   off += (size_t)G * 4;
    size_t zbytes = off;                              // contiguous zero region: segsum + cum
    off = (off + 255) & ~(size_t)255;
    int* bsum   = (int*)(ws + off); off += 64 * 4;          off = (off + 255) & ~(size_t)255;
    int* gid    = (int*)(ws + off); off += (size_t)N * 4;   off = (off + 255) & ~(size_t)255;
    int* gstart = (int*)(ws + off); off += (size_t)(G + 1) * 4; off = (off + 255) & ~(size_t)255;
    int* ngr    = (int*)(ws + off); off += 256;
    unsigned short* W1a = (unsigned short*)(ws + off); off += (size_t)H * H * 2;
    unsigned short* W1b = (unsigned short*)(ws + off); off += (size_t)H * H * 2;
    unsigned short* W2a = (unsigned short*)(ws + off); off += (size_t)H * H * 2;
    unsigned short* W2b = (unsigned short*)(ws + off); off += (size_t)H * H * 2;

    int n16 = (int)(zbytes / 16);
    int nb = (G + 1023) >> 10;
    int ntN = (N + 15) >> 4;
    int ntG = (G + 15) >> 4;
    k_zero<<<(n16 + 255) / 256, 256, 0, stream>>>((uint4*)ws, n16);
    k_convw<<<H, 256, 0, stream>>>(W1, W2, W1a, W1b, W2a, W2b);
    k_mark<<<(N + 255) / 256, 256, 0, stream>>>(ids, cum, N);
    k_scan1<<<nb, 256, 0, stream>>>(cum, bsum, G);
    k_scan2<<<1, 64, 0, stream>>>(bsum, nb);
    k_gid<<<(N + 255) / 256, 256, 0, stream>>>(ids, cum, bsum, gid, gstart, ngr, N);
    k_egemm<<<512, 256, 0, stream>>>(emb, W1b, E1, G);
    k_xgemm<<<2048, 256, 0, stream>>>(x, W1a, gid, E1, b1, out, segsum, N);
    k_igemm<<<(ntG + 1) / 2, 256, 0, stream>>>(emb, segsum, W2a, W2b, b2, gstart, ngr, out2, G);
}

// Round 4
// 462.353 us; speedup vs baseline: 1.6019x; 1.6019x over previous
//
#include <hip/hip_runtime.h>

typedef __attribute__((ext_vector_type(8))) short short8;
typedef __attribute__((ext_vector_type(4))) float f32x4;
typedef unsigned long long ull;

static __device__ __forceinline__ unsigned short f2bf(float f) {
    union { float f; unsigned int u; } v; v.f = f;
    unsigned int r = v.u + 0x7fffu + ((v.u >> 16) & 1u);  // RNE
    return (unsigned short)(r >> 16);
}

static __device__ __forceinline__ short8 pack8(float4 a, float4 b) {
    short8 r;
    r[0] = (short)f2bf(a.x); r[1] = (short)f2bf(a.y);
    r[2] = (short)f2bf(a.z); r[3] = (short)f2bf(a.w);
    r[4] = (short)f2bf(b.x); r[5] = (short)f2bf(b.y);
    r[6] = (short)f2bf(b.z); r[7] = (short)f2bf(b.w);
    return r;
}

static __device__ __forceinline__ void dma16(const void* g, void* l) {
    __builtin_amdgcn_global_load_lds(
        (const __attribute__((address_space(1))) unsigned int*)g,
        (__attribute__((address_space(3))) unsigned int*)l, 16, 0, 0);
}

// DMA one 32-row f32 chunk (16KB) into LDS with row-XOR swizzle.
// LDS dest stays linear (global_load_lds requirement); source address is
// pre-swizzled: logical byte L = r*512 + c stored at L ^ ((r&7)<<4).
static __device__ __forceinline__ void dma_chunk(const float* __restrict__ src,
                                                 char* ldsbase, long long grow0,
                                                 long long nrows, int wid, int lane) {
#pragma unroll
    for (int k = 0; k < 4; ++k) {
        int doff = wid * 4096 + k * 1024 + lane * 16;   // dest byte offset in chunk
        int r = doff >> 9;                               // logical row of this 16B
        long long srcb = (grow0 + r) * 512 + (long long)((doff & 511) ^ ((r & 7) << 4));
        long long maxb = nrows * 512 - 16;
        srcb = srcb < maxb ? srcb : maxb;                // clamp OOB rows (garbage ok)
        dma16((const char*)src + srcb, ldsbase + wid * 4096 + k * 1024);
    }
}

static __device__ __forceinline__ float4 lds_rd16(const float* buf, int boff, int sw) {
    return *(const float4*)((const char*)buf + (boff ^ sw));
}

__global__ void k_zero(uint4* p, int n16) {
    int i = blockIdx.x * blockDim.x + threadIdx.x;
    if (i < n16) p[i] = uint4{0u, 0u, 0u, 0u};
}

// W1,W2 (f32 [128][256]) -> 4 bf16 [128][128] row-major (row j = output col j)
__global__ void k_convw(const float* __restrict__ W1, const float* __restrict__ W2,
                        unsigned short* W1a, unsigned short* W1b,
                        unsigned short* W2a, unsigned short* W2b) {
    int j = blockIdx.x;
    int k = threadIdx.x;
    float w1 = W1[j * 256 + k], w2 = W2[j * 256 + k];
    if (k < 128) { W1a[j * 128 + k] = f2bf(w1); W2a[j * 128 + k] = f2bf(w2); }
    else         { W1b[j * 128 + k - 128] = f2bf(w1); W2b[j * 128 + k - 128] = f2bf(w2); }
}

__global__ void k_mark(const int* __restrict__ ids, int* __restrict__ cum, int n) {
    int i = blockIdx.x * blockDim.x + threadIdx.x;
    if (i < n) cum[ids[i]] = 1;
}

// 2-level scan: per-block inclusive scan of 1024 ints + block sums
__global__ __launch_bounds__(256) void k_scan1(int* __restrict__ cum, int* __restrict__ bsum, int G) {
    __shared__ int ws[4];
    int tid = threadIdx.x;
    int base = blockIdx.x * 1024 + tid * 4;
    int a0 = 0, a1 = 0, a2 = 0, a3 = 0;
    if (base + 0 < G) a0 = cum[base + 0];
    if (base + 1 < G) a1 = cum[base + 1];
    if (base + 2 < G) a2 = cum[base + 2];
    if (base + 3 < G) a3 = cum[base + 3];
    int s = a0 + a1 + a2 + a3;
    int lane = tid & 63;
    int v = s;
#pragma unroll
    for (int off = 1; off < 64; off <<= 1) {
        int u = __shfl_up(v, off, 64);
        if (lane >= off) v += u;
    }
    if (lane == 63) ws[tid >> 6] = v;
    __syncthreads();
    int wof = 0;
    for (int w = 0; w < (tid >> 6); ++w) wof += ws[w];
    int excl = wof + v - s;
    int r0 = excl + a0, r1 = r0 + a1, r2 = r1 + a2, r3 = r2 + a3;
    if (base + 0 < G) cum[base + 0] = r0;
    if (base + 1 < G) cum[base + 1] = r1;
    if (base + 2 < G) cum[base + 2] = r2;
    if (base + 3 < G) cum[base + 3] = r3;
    if (tid == 255) bsum[blockIdx.x] = excl + s;
}

__global__ void k_scan2(int* __restrict__ bsum, int nb) {
    int t = threadIdx.x;  // 64 threads, nb <= 64
    int v = (t < nb) ? bsum[t] : 0;
#pragma unroll
    for (int off = 1; off < 64; off <<= 1) {
        int u = __shfl_up(v, off, 64);
        if (t >= off) v += u;
    }
    if (t < nb) bsum[t] = v;
}

__global__ void k_gid(const int* __restrict__ ids, const int* __restrict__ cum,
                      const int* __restrict__ bsum, int* __restrict__ gid,
                      int* __restrict__ gstart, int* __restrict__ ngr, int n) {
    int i = blockIdx.x * blockDim.x + threadIdx.x;
    if (i >= n) return;
    int v = ids[i];
    int blk = v >> 10;
    int g = cum[v] + (blk ? bsum[blk - 1] : 0) - 1;
    gid[i] = g;
    if (i == 0 || ids[i - 1] != v) gstart[g] = i;
    if (i == n - 1) { gstart[g + 1] = n; *ngr = g + 1; }
}

// E1 = emb @ W1b^T. One 16-row tile per wave-pair, direct register loads.
__global__ __launch_bounds__(256) void k_egemm(
    const float* __restrict__ emb, const unsigned short* __restrict__ W1b,
    float* __restrict__ E1, int G) {
    int tid = threadIdx.x, lane = tid & 63, wid = tid >> 6;
    int p = lane & 15, q = lane >> 4;
    int wr = wid >> 1, wc = wid & 1;
    int nt = (G + 15) >> 4;
    int t0 = blockIdx.x * 2 + wr;
    if (t0 >= nt) return;

    short8 bfr[4][4];
#pragma unroll
    for (int t = 0; t < 4; ++t)
#pragma unroll
        for (int kk = 0; kk < 4; ++kk)
            bfr[t][kk] = *(const short8*)&W1b[(size_t)(wc * 64 + t * 16 + p) * 128 + kk * 32 + q * 8];

    size_t rc = (size_t)min(t0 * 16 + p, G - 1) * 128;
    short8 afr[4];
#pragma unroll
    for (int kk = 0; kk < 4; ++kk) {
        float4 v0 = *(const float4*)(emb + rc + kk * 32 + q * 8);
        float4 v1 = *(const float4*)(emb + rc + kk * 32 + q * 8 + 4);
        afr[kk] = pack8(v0, v1);
    }
    f32x4 acc[4];
#pragma unroll
    for (int t = 0; t < 4; ++t) acc[t] = f32x4{0.f, 0.f, 0.f, 0.f};
#pragma unroll
    for (int t = 0; t < 4; ++t)
#pragma unroll
        for (int kk = 0; kk < 4; ++kk)
            acc[t] = __builtin_amdgcn_mfma_f32_16x16x32_bf16(afr[kk], bfr[t][kk], acc[t], 0, 0, 0);
#pragma unroll
    for (int t = 0; t < 4; ++t) {
        int colb = wc * 64 + t * 16 + p;
#pragma unroll
        for (int rg = 0; rg < 4; ++rg) {
            int rr = t0 * 16 + q * 4 + rg;
            if (rr < G) E1[(size_t)rr * 128 + colb] = acc[t][rg];
        }
    }
}

// x_out = x @ W1a^T + E1[gid] + b1, fused segment sums.
// DMA double-buffer; per-chunk sync is s_waitcnt vmcnt(32)+s_barrier: the >=32
// side-effecting vmem ops (16 atomics + 16 stores) issued AFTER the 4 DMA ops
// guarantee (in-order vmcnt retire) the DMAs landed without draining own stores.
__global__ __launch_bounds__(256, 3) void k_xgemm(
    const float* __restrict__ x, const unsigned short* __restrict__ W1a,
    const int* __restrict__ gid, const float* __restrict__ E1,
    const float* __restrict__ b1, float* __restrict__ out,
    float* __restrict__ segsum, int N) {
    __shared__ __align__(16) float xbuf[2][4096];
    int tid = threadIdx.x, lane = tid & 63, wid = tid >> 6;
    int p = lane & 15, q = lane >> 4;
    int wr = wid >> 1, wc = wid & 1;
    long long row0 = (long long)blockIdx.x * 256;
    int sw = (p & 7) << 4;

    short8 bfr[4][4];
#pragma unroll
    for (int t = 0; t < 4; ++t)
#pragma unroll
        for (int kk = 0; kk < 4; ++kk)
            bfr[t][kk] = *(const short8*)&W1a[(size_t)(wc * 64 + t * 16 + p) * 128 + kk * 32 + q * 8];
    float b1v[4];
#pragma unroll
    for (int t = 0; t < 4; ++t) b1v[t] = b1[wc * 64 + t * 16 + p];

    dma_chunk(x, (char*)&xbuf[0][0], row0, N, wid, lane);
    asm volatile("" ::: "memory");
    asm volatile("s_waitcnt vmcnt(0)" ::: "memory");
    __builtin_amdgcn_s_barrier();
    __builtin_amdgcn_sched_barrier(0);

    for (int c = 0; c < 8; ++c) {
        if (c < 7)
            dma_chunk(x, (char*)&xbuf[(c + 1) & 1][0], row0 + (long long)(c + 1) * 32, N, wid, lane);
        asm volatile("" ::: "memory");   // pin DMA issue before all epilogue vmem

        const float* xb = &xbuf[c & 1][0];
        int grB = (int)row0 + c * 32;
        int myrow = grB + wr * 16 + p;
        int rowc = myrow < N ? myrow : N - 1;
        int g = gid[rowc];

        // segment boundary prep (rows = p within this wave's 16-row half)
        int gpv = __shfl(g, lane > 0 ? lane - 1 : 0);
        int gnx = __shfl(g, lane < 63 ? lane + 1 : 63);
        bool is_start = (p == 0) || (gpv != g);
        bool is_end = (p == 15) || (gnx != g);
        ull smask = __ballot(is_start);
        ull below = smask & (~0ULL >> (63 - lane));
        int startlane = 63 - __builtin_clzll(below);
        bool has_before = (startlane & 15) != 0;
        int pbl = startlane > 0 ? startlane - 1 : 0;

        // LDS -> fragments (+ keep f32 of this wave's two owned kk for the scan)
        short8 afr[4];
        float sv[2][8];
#pragma unroll
        for (int kk = 0; kk < 4; ++kk) {
            int boff = (wr * 16 + p) * 512 + kk * 128 + q * 32;
            float4 v0 = lds_rd16(xb, boff, sw);
            float4 v1 = lds_rd16(xb, boff + 16, sw);
            afr[kk] = pack8(v0, v1);
            if ((kk >> 1) == wc) {
                int kx = kk & 1;
                sv[kx][0] = v0.x; sv[kx][1] = v0.y; sv[kx][2] = v0.z; sv[kx][3] = v0.w;
                sv[kx][4] = v1.x; sv[kx][5] = v1.y; sv[kx][6] = v1.z; sv[kx][7] = v1.w;
            }
        }
        if (myrow >= N) {
#pragma unroll
            for (int kx = 0; kx < 2; ++kx)
#pragma unroll
                for (int j = 0; j < 8; ++j) sv[kx][j] = 0.f;
        }

        // segmented inclusive scan over 16 row-lanes; boundary atomics (16 insts)
#pragma unroll
        for (int kx = 0; kx < 2; ++kx) {
            int kk = wc * 2 + kx;
            float v[8];
#pragma unroll
            for (int j = 0; j < 8; ++j) v[j] = sv[kx][j];
#pragma unroll
            for (int j = 0; j < 8; ++j) { float u = __shfl_up(v[j], 1, 16); if (p >= 1) v[j] += u; }
#pragma unroll
            for (int j = 0; j < 8; ++j) { float u = __shfl_up(v[j], 2, 16); if (p >= 2) v[j] += u; }
#pragma unroll
            for (int j = 0; j < 8; ++j) { float u = __shfl_up(v[j], 4, 16); if (p >= 4) v[j] += u; }
#pragma unroll
            for (int j = 0; j < 8; ++j) { float u = __shfl_up(v[j], 8, 16); if (p >= 8) v[j] += u; }
#pragma unroll
            for (int j = 0; j < 8; ++j) {
                float pb = __shfl(v[j], pbl);
                if (is_end) {
                    float seg = v[j] - (has_before ? pb : 0.f);
                    atomicAdd(&segsum[(size_t)g * 128 + kk * 32 + q * 8 + j], seg);
                }
            }
        }

        f32x4 acc[4];
#pragma unroll
        for (int t = 0; t < 4; ++t) acc[t] = f32x4{0.f, 0.f, 0.f, 0.f};
#pragma unroll
        for (int t = 0; t < 4; ++t)
#pragma unroll
            for (int kk = 0; kk < 4; ++kk)
                acc[t] = __builtin_amdgcn_mfma_f32_16x16x32_bf16(afr[kk], bfr[t][kk], acc[t], 0, 0, 0);

        int g4[4];
#pragma unroll
        for (int rg = 0; rg < 4; ++rg) g4[rg] = __shfl(g, q * 4 + rg);
#pragma unroll
        for (int t = 0; t < 4; ++t) {
            int colb = wc * 64 + t * 16 + p;
#pragma unroll
            for (int rg = 0; rg < 4; ++rg) {
                int rr = grB + wr * 16 + q * 4 + rg;
                if (rr < N)
                    out[(size_t)rr * 128 + colb] = acc[t][rg] + E1[(size_t)g4[rg] * 128 + colb] + b1v[t];
            }
        }

        if (c < 7) {
            asm volatile("s_waitcnt vmcnt(32)" ::: "memory");  // DMAs retired; own stores NOT drained
            __builtin_amdgcn_s_barrier();
            __builtin_amdgcn_sched_barrier(0);
        }
    }
}

// imputed_out = emb @ W2a^T + imp_second @ W2b^T + b2, mean computed in-register.
__global__ __launch_bounds__(256, 2) void k_igemm(
    const float* __restrict__ emb, const float* __restrict__ segsum,
    const unsigned short* __restrict__ W2a, const unsigned short* __restrict__ W2b,
    const float* __restrict__ b2, const int* __restrict__ gstart,
    const int* __restrict__ ngr, float* __restrict__ out2, int G) {
    int tid = threadIdx.x, lane = tid & 63, wid = tid >> 6;
    int p = lane & 15, q = lane >> 4;
    int wr = wid >> 1, wc = wid & 1;
    int nt = (G + 15) >> 4;
    int t0 = blockIdx.x * 2 + wr;
    if (t0 >= nt) return;
    int ng = *ngr;

    short8 bfrA[4][4], bfrB[4][4];
#pragma unroll
    for (int t = 0; t < 4; ++t)
#pragma unroll
        for (int kk = 0; kk < 4; ++kk) {
            bfrA[t][kk] = *(const short8*)&W2a[(size_t)(wc * 64 + t * 16 + p) * 128 + kk * 32 + q * 8];
            bfrB[t][kk] = *(const short8*)&W2b[(size_t)(wc * 64 + t * 16 + p) * 128 + kk * 32 + q * 8];
        }
    float b2v[4];
#pragma unroll
    for (int t = 0; t < 4; ++t) b2v[t] = b2[wc * 64 + t * 16 + p];

    int rowc = min(t0 * 16 + p, G - 1);
    bool written = rowc < ng - 1;
    int cnt = gstart[rowc + 1] - gstart[rowc];  // garbage if !written (unused)
    float inv = written ? 1.0f / (float)(cnt > 0 ? cnt : 1) : 0.f;

    f32x4 acc[4];
#pragma unroll
    for (int t = 0; t < 4; ++t) acc[t] = f32x4{0.f, 0.f, 0.f, 0.f};
    size_t rc = (size_t)rowc * 128;
#pragma unroll
    for (int kk = 0; kk < 4; ++kk) {
        float4 e0 = *(const float4*)(emb + rc + kk * 32 + q * 8);
        float4 e1 = *(const float4*)(emb + rc + kk * 32 + q * 8 + 4);
        float4 s0 = *(const float4*)(segsum + rc + kk * 32 + q * 8);
        float4 s1 = *(const float4*)(segsum + rc + kk * 32 + q * 8 + 4);
        short8 ae = pack8(e0, e1);
        float4 m0, m1;
        m0.x = written ? s0.x * inv : e0.x; m0.y = written ? s0.y * inv : e0.y;
        m0.z = written ? s0.z * inv : e0.z; m0.w = written ? s0.w * inv : e0.w;
        m1.x = written ? s1.x * inv : e1.x; m1.y = written ? s1.y * inv : e1.y;
        m1.z = written ? s1.z * inv : e1.z; m1.w = written ? s1.w * inv : e1.w;
        short8 am = pack8(m0, m1);
#pragma unroll
        for (int t = 0; t < 4; ++t) {
            acc[t] = __builtin_amdgcn_mfma_f32_16x16x32_bf16(ae, bfrA[t][kk], acc[t], 0, 0, 0);
            acc[t] = __builtin_amdgcn_mfma_f32_16x16x32_bf16(am, bfrB[t][kk], acc[t], 0, 0, 0);
        }
    }
#pragma unroll
    for (int t = 0; t < 4; ++t) {
        int colb = wc * 64 + t * 16 + p;
#pragma unroll
        for (int rg = 0; rg < 4; ++rg) {
            int rr = t0 * 16 + q * 4 + rg;
            if (rr < G) out2[(size_t)rr * 128 + colb] = acc[t][rg] + b2v[t];
        }
    }
}

extern "C" void kernel_launch(void* const* d_in, const int* in_sizes, int n_in,
                              void* d_out, int out_size, void* d_ws, size_t ws_size,
                              hipStream_t stream) {
    const float* x   = (const float*)d_in[0];
    const float* emb = (const float*)d_in[1];
    const float* W1  = (const float*)d_in[2];
    const float* b1  = (const float*)d_in[3];
    const float* W2  = (const float*)d_in[4];
    const float* b2  = (const float*)d_in[5];
    const int*   ids = (const int*)d_in[6];
    const int H = 128;
    const int N = in_sizes[6];
    const int G = in_sizes[1] / H;

    float* out  = (float*)d_out;
    float* out2 = out + (size_t)N * H;
    float* E1   = out2;  // E1 scratch lives in imputed_out region (overwritten by k_igemm last)

    char* ws = (char*)d_ws;
    size_t off = 0;
    float* segsum = (float*)(ws + off); off += (size_t)G * H * 4;
    int*   cum    = (int*)(ws + off);   off += (size_t)G * 4;
    size_t zbytes = off;                              // contiguous zero region: segsum + cum
    off = (off + 255) & ~(size_t)255;
    int* bsum   = (int*)(ws + off); off += 64 * 4;          off = (off + 255) & ~(size_t)255;
    int* gid    = (int*)(ws + off); off += (size_t)N * 4;   off = (off + 255) & ~(size_t)255;
    int* gstart = (int*)(ws + off); off += (size_t)(G + 1) * 4; off = (off + 255) & ~(size_t)255;
    int* ngr    = (int*)(ws + off); off += 256;
    unsigned short* W1a = (unsigned short*)(ws + off); off += (size_t)H * H * 2;
    unsigned short* W1b = (unsigned short*)(ws + off); off += (size_t)H * H * 2;
    unsigned short* W2a = (unsigned short*)(ws + off); off += (size_t)H * H * 2;
    unsigned short* W2b = (unsigned short*)(ws + off); off += (size_t)H * H * 2;

    int n16 = (int)(zbytes / 16);
    int nb = (G + 1023) >> 10;
    int ntG = (G + 15) >> 4;
    k_zero<<<(n16 + 255) / 256, 256, 0, stream>>>((uint4*)ws, n16);
    k_convw<<<H, 256, 0, stream>>>(W1, W2, W1a, W1b, W2a, W2b);
    k_mark<<<(N + 255) / 256, 256, 0, stream>>>(ids, cum, N);
    k_scan1<<<nb, 256, 0, stream>>>(cum, bsum, G);
    k_scan2<<<1, 64, 0, stream>>>(bsum, nb);
    k_gid<<<(N + 255) / 256, 256, 0, stream>>>(ids, cum, bsum, gid, gstart, ngr, N);
    k_egemm<<<(ntG + 1) / 2, 256, 0, stream>>>(emb, W1b, E1, G);
    k_xgemm<<<(N + 255) / 256, 256, 0, stream>>>(x, W1a, gid, E1, b1, out, segsum, N);
    k_igemm<<<(ntG + 1) / 2, 256, 0, stream>>>(emb, segsum, W2a, W2b, b2, gstart, ngr, out2, G);
}

// Round 5
// 353.650 us; speedup vs baseline: 2.0943x; 1.3074x over previous
//
#include <hip/hip_runtime.h>

typedef __attribute__((ext_vector_type(8))) short short8;
typedef __attribute__((ext_vector_type(4))) float f32x4;

static __device__ __forceinline__ unsigned short f2bf(float f) {
    union { float f; unsigned int u; } v; v.f = f;
    unsigned int r = v.u + 0x7fffu + ((v.u >> 16) & 1u);  // RNE
    return (unsigned short)(r >> 16);
}

static __device__ __forceinline__ short8 pack8(float4 a, float4 b) {
    short8 r;
    r[0] = (short)f2bf(a.x); r[1] = (short)f2bf(a.y);
    r[2] = (short)f2bf(a.z); r[3] = (short)f2bf(a.w);
    r[4] = (short)f2bf(b.x); r[5] = (short)f2bf(b.y);
    r[6] = (short)f2bf(b.z); r[7] = (short)f2bf(b.w);
    return r;
}

__global__ void k_zero(uint4* p, int n16) {
    int i = blockIdx.x * blockDim.x + threadIdx.x;
    if (i < n16) p[i] = uint4{0u, 0u, 0u, 0u};
}

// W1,W2 (f32 [128][256]) -> 4 bf16 [128][128] row-major (row j = output col j)
__global__ void k_convw(const float* __restrict__ W1, const float* __restrict__ W2,
                        unsigned short* W1a, unsigned short* W1b,
                        unsigned short* W2a, unsigned short* W2b) {
    int j = blockIdx.x;
    int k = threadIdx.x;
    float w1 = W1[j * 256 + k], w2 = W2[j * 256 + k];
    if (k < 128) { W1a[j * 128 + k] = f2bf(w1); W2a[j * 128 + k] = f2bf(w2); }
    else         { W1b[j * 128 + k - 128] = f2bf(w1); W2b[j * 128 + k - 128] = f2bf(w2); }
}

__global__ void k_mark(const int* __restrict__ ids, int* __restrict__ cum, int n) {
    int i = blockIdx.x * blockDim.x + threadIdx.x;
    if (i < n) cum[ids[i]] = 1;
}

// 2-level scan: per-block inclusive scan of 1024 ints + block sums
__global__ __launch_bounds__(256) void k_scan1(int* __restrict__ cum, int* __restrict__ bsum, int G) {
    __shared__ int ws[4];
    int tid = threadIdx.x;
    int base = blockIdx.x * 1024 + tid * 4;
    int a0 = 0, a1 = 0, a2 = 0, a3 = 0;
    if (base + 0 < G) a0 = cum[base + 0];
    if (base + 1 < G) a1 = cum[base + 1];
    if (base + 2 < G) a2 = cum[base + 2];
    if (base + 3 < G) a3 = cum[base + 3];
    int s = a0 + a1 + a2 + a3;
    int lane = tid & 63;
    int v = s;
#pragma unroll
    for (int off = 1; off < 64; off <<= 1) {
        int u = __shfl_up(v, off, 64);
        if (lane >= off) v += u;
    }
    if (lane == 63) ws[tid >> 6] = v;
    __syncthreads();
    int wof = 0;
    for (int w = 0; w < (tid >> 6); ++w) wof += ws[w];
    int excl = wof + v - s;
    int r0 = excl + a0, r1 = r0 + a1, r2 = r1 + a2, r3 = r2 + a3;
    if (base + 0 < G) cum[base + 0] = r0;
    if (base + 1 < G) cum[base + 1] = r1;
    if (base + 2 < G) cum[base + 2] = r2;
    if (base + 3 < G) cum[base + 3] = r3;
    if (tid == 255) bsum[blockIdx.x] = excl + s;
}

__global__ void k_scan2(int* __restrict__ bsum, int nb) {
    int t = threadIdx.x;  // 64 threads, nb <= 64
    int v = (t < nb) ? bsum[t] : 0;
#pragma unroll
    for (int off = 1; off < 64; off <<= 1) {
        int u = __shfl_up(v, off, 64);
        if (t >= off) v += u;
    }
    if (t < nb) bsum[t] = v;
}

__global__ void k_gid(const int* __restrict__ ids, const int* __restrict__ cum,
                      const int* __restrict__ bsum, int* __restrict__ gid,
                      int* __restrict__ gstart, int* __restrict__ ngr, int n) {
    int i = blockIdx.x * blockDim.x + threadIdx.x;
    if (i >= n) return;
    int v = ids[i];
    int blk = v >> 10;
    int g = cum[v] + (blk ? bsum[blk - 1] : 0) - 1;
    gid[i] = g;
    if (i == 0 || ids[i - 1] != v) gstart[g] = i;
    if (i == n - 1) { gstart[g + 1] = n; *ngr = g + 1; }
}

// imp_second (bf16) per group: one WAVE per group, rows contiguous (sorted ids).
// No atomics. lane = column pair (float2 = 8B/lane -> 512B/row coalesced).
__global__ __launch_bounds__(256) void k_gsum(
    const float* __restrict__ x, const float* __restrict__ emb,
    const int* __restrict__ gstart, const int* __restrict__ ngr,
    unsigned short* __restrict__ imps, int G) {
    int w = blockIdx.x * 4 + (threadIdx.x >> 6);   // wave id = group slot
    int lane = threadIdx.x & 63;
    if (w >= G) return;
    int ng = *ngr;
    float2 m;
    if (w < ng - 1) {
        int a = gstart[w], b = gstart[w + 1];
        const float* px = x + (size_t)a * 128 + lane * 2;
        int n = b - a;
        float2 s = {0.f, 0.f};
        float2 nxt = *(const float2*)px;          // 2-deep pipelined row walk
        for (int r = 0; r < n; ++r) {
            float2 cur = nxt;
            if (r + 1 < n) nxt = *(const float2*)(px + (size_t)(r + 1) * 128);
            s.x += cur.x; s.y += cur.y;
        }
        float inv = 1.0f / (float)n;
        m.x = s.x * inv; m.y = s.y * inv;
    } else {
        m = *(const float2*)(emb + (size_t)w * 128 + lane * 2);
    }
    unsigned int pk = (unsigned int)f2bf(m.x) | ((unsigned int)f2bf(m.y) << 16);
    ((unsigned int*)imps)[(size_t)w * 64 + lane] = pk;
}

// E1 = emb @ W1b^T + b1 (b1 folded). One-shot 16-row tile per wave-pair.
__global__ __launch_bounds__(256) void k_egemm(
    const float* __restrict__ emb, const unsigned short* __restrict__ W1b,
    const float* __restrict__ b1, float* __restrict__ E1, int G) {
    int tid = threadIdx.x, lane = tid & 63, wid = tid >> 6;
    int p = lane & 15, q = lane >> 4;
    int wr = wid >> 1, wc = wid & 1;
    int nt = (G + 15) >> 4;
    int t0 = blockIdx.x * 2 + wr;
    if (t0 >= nt) return;

    size_t rc = (size_t)min(t0 * 16 + p, G - 1) * 128;
    float4 xv[8];
#pragma unroll
    for (int kk = 0; kk < 4; ++kk) {
        xv[2 * kk]     = *(const float4*)(emb + rc + kk * 32 + q * 8);
        xv[2 * kk + 1] = *(const float4*)(emb + rc + kk * 32 + q * 8 + 4);
    }
    short8 bfr[4][4];
#pragma unroll
    for (int t = 0; t < 4; ++t)
#pragma unroll
        for (int kk = 0; kk < 4; ++kk)
            bfr[t][kk] = *(const short8*)&W1b[(size_t)(wc * 64 + t * 16 + p) * 128 + kk * 32 + q * 8];
    float b1v[4];
#pragma unroll
    for (int t = 0; t < 4; ++t) b1v[t] = b1[wc * 64 + t * 16 + p];

    short8 afr[4];
#pragma unroll
    for (int kk = 0; kk < 4; ++kk) afr[kk] = pack8(xv[2 * kk], xv[2 * kk + 1]);
    f32x4 acc[4];
#pragma unroll
    for (int t = 0; t < 4; ++t) acc[t] = f32x4{0.f, 0.f, 0.f, 0.f};
#pragma unroll
    for (int t = 0; t < 4; ++t)
#pragma unroll
        for (int kk = 0; kk < 4; ++kk)
            acc[t] = __builtin_amdgcn_mfma_f32_16x16x32_bf16(afr[kk], bfr[t][kk], acc[t], 0, 0, 0);
#pragma unroll
    for (int t = 0; t < 4; ++t) {
        int colb = wc * 64 + t * 16 + p;
#pragma unroll
        for (int rg = 0; rg < 4; ++rg) {
            int rr = t0 * 16 + q * 4 + rg;
            if (rr < G) E1[(size_t)rr * 128 + colb] = acc[t][rg] + b1v[t];
        }
    }
}

// x_out = x @ W1a^T + E1[gid]  (E1 already includes b1). One-shot tile,
// no LDS, no barriers, no atomics: waves fully independent, TLP hides latency.
__global__ __launch_bounds__(256) void k_xgemm(
    const float* __restrict__ x, const unsigned short* __restrict__ W1a,
    const int* __restrict__ gid, const float* __restrict__ E1,
    float* __restrict__ out, int N) {
    int tid = threadIdx.x, lane = tid & 63, wid = tid >> 6;
    int p = lane & 15, q = lane >> 4;
    int wr = wid >> 1, wc = wid & 1;
    int nt = (N + 15) >> 4;
    int t0 = blockIdx.x * 2 + wr;
    if (t0 >= nt) return;

    int myrow = t0 * 16 + p;
    int rowc = myrow < N ? myrow : N - 1;
    int g = gid[rowc];                         // issue first: heads the E1 chain

    size_t rc = (size_t)rowc * 128;
    float4 xv[8];
#pragma unroll
    for (int kk = 0; kk < 4; ++kk) {
        xv[2 * kk]     = *(const float4*)(x + rc + kk * 32 + q * 8);
        xv[2 * kk + 1] = *(const float4*)(x + rc + kk * 32 + q * 8 + 4);
    }
    short8 bfr[4][4];
#pragma unroll
    for (int t = 0; t < 4; ++t)
#pragma unroll
        for (int kk = 0; kk < 4; ++kk)
            bfr[t][kk] = *(const short8*)&W1a[(size_t)(wc * 64 + t * 16 + p) * 128 + kk * 32 + q * 8];

    int g4[4];
#pragma unroll
    for (int rg = 0; rg < 4; ++rg) g4[rg] = __shfl(g, q * 4 + rg);
    float ev[4][4];                            // E1 gather issued before MFMA
#pragma unroll
    for (int t = 0; t < 4; ++t) {
        int colb = wc * 64 + t * 16 + p;
#pragma unroll
        for (int rg = 0; rg < 4; ++rg)
            ev[t][rg] = E1[(size_t)g4[rg] * 128 + colb];
    }

    short8 afr[4];
#pragma unroll
    for (int kk = 0; kk < 4; ++kk) afr[kk] = pack8(xv[2 * kk], xv[2 * kk + 1]);
    f32x4 acc[4];
#pragma unroll
    for (int t = 0; t < 4; ++t) acc[t] = f32x4{0.f, 0.f, 0.f, 0.f};
#pragma unroll
    for (int t = 0; t < 4; ++t)
#pragma unroll
        for (int kk = 0; kk < 4; ++kk)
            acc[t] = __builtin_amdgcn_mfma_f32_16x16x32_bf16(afr[kk], bfr[t][kk], acc[t], 0, 0, 0);
#pragma unroll
    for (int t = 0; t < 4; ++t) {
        int colb = wc * 64 + t * 16 + p;
#pragma unroll
        for (int rg = 0; rg < 4; ++rg) {
            int rr = t0 * 16 + q * 4 + rg;
            if (rr < N) out[(size_t)rr * 128 + colb] = acc[t][rg] + ev[t][rg];
        }
    }
}

// imputed_out = emb @ W2a^T + imps @ W2b^T + b2. One-shot tile per wave-pair.
__global__ __launch_bounds__(256) void k_igemm(
    const float* __restrict__ emb, const unsigned short* __restrict__ imps,
    const unsigned short* __restrict__ W2a, const unsigned short* __restrict__ W2b,
    const float* __restrict__ b2, float* __restrict__ out2, int G) {
    int tid = threadIdx.x, lane = tid & 63, wid = tid >> 6;
    int p = lane & 15, q = lane >> 4;
    int wr = wid >> 1, wc = wid & 1;
    int nt = (G + 15) >> 4;
    int t0 = blockIdx.x * 2 + wr;
    if (t0 >= nt) return;

    int rowc = min(t0 * 16 + p, G - 1);
    size_t rc = (size_t)rowc * 128;
    float4 xv[8];
    short8 ia[4];
#pragma unroll
    for (int kk = 0; kk < 4; ++kk) {
        xv[2 * kk]     = *(const float4*)(emb + rc + kk * 32 + q * 8);
        xv[2 * kk + 1] = *(const float4*)(emb + rc + kk * 32 + q * 8 + 4);
        ia[kk] = *(const short8*)&imps[rc + kk * 32 + q * 8];
    }
    short8 bfrA[4][4], bfrB[4][4];
#pragma unroll
    for (int t = 0; t < 4; ++t)
#pragma unroll
        for (int kk = 0; kk < 4; ++kk) {
            bfrA[t][kk] = *(const short8*)&W2a[(size_t)(wc * 64 + t * 16 + p) * 128 + kk * 32 + q * 8];
            bfrB[t][kk] = *(const short8*)&W2b[(size_t)(wc * 64 + t * 16 + p) * 128 + kk * 32 + q * 8];
        }
    float b2v[4];
#pragma unroll
    for (int t = 0; t < 4; ++t) b2v[t] = b2[wc * 64 + t * 16 + p];

    f32x4 acc[4];
#pragma unroll
    for (int t = 0; t < 4; ++t) acc[t] = f32x4{0.f, 0.f, 0.f, 0.f};
#pragma unroll
    for (int kk = 0; kk < 4; ++kk) {
        short8 ae = pack8(xv[2 * kk], xv[2 * kk + 1]);
#pragma unroll
        for (int t = 0; t < 4; ++t) {
            acc[t] = __builtin_amdgcn_mfma_f32_16x16x32_bf16(ae, bfrA[t][kk], acc[t], 0, 0, 0);
            acc[t] = __builtin_amdgcn_mfma_f32_16x16x32_bf16(ia[kk], bfrB[t][kk], acc[t], 0, 0, 0);
        }
    }
#pragma unroll
    for (int t = 0; t < 4; ++t) {
        int colb = wc * 64 + t * 16 + p;
#pragma unroll
        for (int rg = 0; rg < 4; ++rg) {
            int rr = t0 * 16 + q * 4 + rg;
            if (rr < G) out2[(size_t)rr * 128 + colb] = acc[t][rg] + b2v[t];
        }
    }
}

extern "C" void kernel_launch(void* const* d_in, const int* in_sizes, int n_in,
                              void* d_out, int out_size, void* d_ws, size_t ws_size,
                              hipStream_t stream) {
    const float* x   = (const float*)d_in[0];
    const float* emb = (const float*)d_in[1];
    const float* W1  = (const float*)d_in[2];
    const float* b1  = (const float*)d_in[3];
    const float* W2  = (const float*)d_in[4];
    const float* b2  = (const float*)d_in[5];
    const int*   ids = (const int*)d_in[6];
    const int H = 128;
    const int N = in_sizes[6];
    const int G = in_sizes[1] / H;

    float* out  = (float*)d_out;
    float* out2 = out + (size_t)N * H;
    float* E1   = out2;  // E1 scratch lives in imputed_out region (overwritten by k_igemm last)

    char* ws = (char*)d_ws;
    size_t off = 0;
    int*   cum    = (int*)(ws + off);   off += (size_t)G * 4;
    size_t zbytes = off;                              // zero region: cum only
    off = (off + 255) & ~(size_t)255;
    int* bsum   = (int*)(ws + off); off += 64 * 4;          off = (off + 255) & ~(size_t)255;
    int* gid    = (int*)(ws + off); off += (size_t)N * 4;   off = (off + 255) & ~(size_t)255;
    int* gstart = (int*)(ws + off); off += (size_t)(G + 1) * 4; off = (off + 255) & ~(size_t)255;
    int* ngr    = (int*)(ws + off); off += 256;
    unsigned short* W1a = (unsigned short*)(ws + off); off += (size_t)H * H * 2;
    unsigned short* W1b = (unsigned short*)(ws + off); off += (size_t)H * H * 2;
    unsigned short* W2a = (unsigned short*)(ws + off); off += (size_t)H * H * 2;
    unsigned short* W2b = (unsigned short*)(ws + off); off += (size_t)H * H * 2;
    unsigned short* imps = (unsigned short*)(ws + off); off += (size_t)G * H * 2;

    int n16 = (int)((zbytes + 15) / 16);
    int nb = (G + 1023) >> 10;
    int ntN = (N + 15) >> 4;
    int ntG = (G + 15) >> 4;
    k_zero<<<(n16 + 255) / 256, 256, 0, stream>>>((uint4*)ws, n16);
    k_convw<<<H, 256, 0, stream>>>(W1, W2, W1a, W1b, W2a, W2b);
    k_mark<<<(N + 255) / 256, 256, 0, stream>>>(ids, cum, N);
    k_scan1<<<nb, 256, 0, stream>>>(cum, bsum, G);
    k_scan2<<<1, 64, 0, stream>>>(bsum, nb);
    k_gid<<<(N + 255) / 256, 256, 0, stream>>>(ids, cum, bsum, gid, gstart, ngr, N);
    k_gsum<<<(G + 3) / 4, 256, 0, stream>>>(x, emb, gstart, ngr, imps, G);
    k_egemm<<<(ntG + 1) / 2, 256, 0, stream>>>(emb, W1b, b1, E1, G);
    k_xgemm<<<(ntN + 1) / 2, 256, 0, stream>>>(x, W1a, gid, E1, out, N);
    k_igemm<<<(ntG + 1) / 2, 256, 0, stream>>>(emb, imps, W2a, W2b, b2, out2, G);
}

// Round 6
// 297.765 us; speedup vs baseline: 2.4874x; 1.1877x over previous
//
#include <hip/hip_runtime.h>

typedef __attribute__((ext_vector_type(8))) short short8;
typedef __attribute__((ext_vector_type(4))) float f32x4;

static __device__ __forceinline__ unsigned short f2bf(float f) {
    union { float f; unsigned int u; } v; v.f = f;
    unsigned int r = v.u + 0x7fffu + ((v.u >> 16) & 1u);  // RNE
    return (unsigned short)(r >> 16);
}

static __device__ __forceinline__ short8 pack8(float4 a, float4 b) {
    short8 r;
    r[0] = (short)f2bf(a.x); r[1] = (short)f2bf(a.y);
    r[2] = (short)f2bf(a.z); r[3] = (short)f2bf(a.w);
    r[4] = (short)f2bf(b.x); r[5] = (short)f2bf(b.y);
    r[6] = (short)f2bf(b.z); r[7] = (short)f2bf(b.w);
    return r;
}

__global__ void k_zero(uint4* p, int n16) {
    int i = blockIdx.x * blockDim.x + threadIdx.x;
    if (i < n16) p[i] = uint4{0u, 0u, 0u, 0u};
}

// W1,W2 (f32 [128][256]) -> 4 bf16 [128][128] row-major (row j = output col j)
__global__ void k_convw(const float* __restrict__ W1, const float* __restrict__ W2,
                        unsigned short* W1a, unsigned short* W1b,
                        unsigned short* W2a, unsigned short* W2b) {
    int j = blockIdx.x;
    int k = threadIdx.x;
    float w1 = W1[j * 256 + k], w2 = W2[j * 256 + k];
    if (k < 128) { W1a[j * 128 + k] = f2bf(w1); W2a[j * 128 + k] = f2bf(w2); }
    else         { W1b[j * 128 + k - 128] = f2bf(w1); W2b[j * 128 + k - 128] = f2bf(w2); }
}

__global__ void k_mark(const int* __restrict__ ids, int* __restrict__ cum, int n) {
    int i = blockIdx.x * blockDim.x + threadIdx.x;
    if (i < n) cum[ids[i]] = 1;
}

// 2-level scan: per-block inclusive scan of 1024 ints + block sums
__global__ __launch_bounds__(256) void k_scan1(int* __restrict__ cum, int* __restrict__ bsum, int G) {
    __shared__ int ws[4];
    int tid = threadIdx.x;
    int base = blockIdx.x * 1024 + tid * 4;
    int a0 = 0, a1 = 0, a2 = 0, a3 = 0;
    if (base + 0 < G) a0 = cum[base + 0];
    if (base + 1 < G) a1 = cum[base + 1];
    if (base + 2 < G) a2 = cum[base + 2];
    if (base + 3 < G) a3 = cum[base + 3];
    int s = a0 + a1 + a2 + a3;
    int lane = tid & 63;
    int v = s;
#pragma unroll
    for (int off = 1; off < 64; off <<= 1) {
        int u = __shfl_up(v, off, 64);
        if (lane >= off) v += u;
    }
    if (lane == 63) ws[tid >> 6] = v;
    __syncthreads();
    int wof = 0;
    for (int w = 0; w < (tid >> 6); ++w) wof += ws[w];
    int excl = wof + v - s;
    int r0 = excl + a0, r1 = r0 + a1, r2 = r1 + a2, r3 = r2 + a3;
    if (base + 0 < G) cum[base + 0] = r0;
    if (base + 1 < G) cum[base + 1] = r1;
    if (base + 2 < G) cum[base + 2] = r2;
    if (base + 3 < G) cum[base + 3] = r3;
    if (tid == 255) bsum[blockIdx.x] = excl + s;
}

__global__ void k_scan2(int* __restrict__ bsum, int nb) {
    int t = threadIdx.x;  // 64 threads, nb <= 64
    int v = (t < nb) ? bsum[t] : 0;
#pragma unroll
    for (int off = 1; off < 64; off <<= 1) {
        int u = __shfl_up(v, off, 64);
        if (t >= off) v += u;
    }
    if (t < nb) bsum[t] = v;
}

__global__ void k_gid(const int* __restrict__ ids, const int* __restrict__ cum,
                      const int* __restrict__ bsum, int* __restrict__ gid,
                      int* __restrict__ gstart, int* __restrict__ ngr, int n) {
    int i = blockIdx.x * blockDim.x + threadIdx.x;
    if (i >= n) return;
    int v = ids[i];
    int blk = v >> 10;
    int g = cum[v] + (blk ? bsum[blk - 1] : 0) - 1;
    gid[i] = g;
    if (i == 0 || ids[i - 1] != v) gstart[g] = i;
    if (i == n - 1) { gstart[g + 1] = n; *ngr = g + 1; }
}

// imp_second (bf16) per group: one WAVE per group, rows contiguous (sorted ids).
// No atomics. lane = column pair (float2 = 8B/lane -> 512B/row coalesced).
__global__ __launch_bounds__(256) void k_gsum(
    const float* __restrict__ x, const float* __restrict__ emb,
    const int* __restrict__ gstart, const int* __restrict__ ngr,
    unsigned short* __restrict__ imps, int G) {
    int w = blockIdx.x * 4 + (threadIdx.x >> 6);   // wave id = group slot
    int lane = threadIdx.x & 63;
    if (w >= G) return;
    int ng = *ngr;
    float2 m;
    if (w < ng - 1) {
        int a = gstart[w], b = gstart[w + 1];
        const float* px = x + (size_t)a * 128 + lane * 2;
        int n = b - a;
        float2 s = {0.f, 0.f};
        float2 nxt = *(const float2*)px;          // 2-deep pipelined row walk
        for (int r = 0; r < n; ++r) {
            float2 cur = nxt;
            if (r + 1 < n) nxt = *(const float2*)(px + (size_t)(r + 1) * 128);
            s.x += cur.x; s.y += cur.y;
        }
        float inv = 1.0f / (float)n;
        m.x = s.x * inv; m.y = s.y * inv;
    } else {
        m = *(const float2*)(emb + (size_t)w * 128 + lane * 2);
    }
    unsigned int pk = (unsigned int)f2bf(m.x) | ((unsigned int)f2bf(m.y) << 16);
    ((unsigned int*)imps)[(size_t)w * 64 + lane] = pk;
}

// E1 = emb @ W1b^T + b1 (b1 folded). One-shot 16-row tile per wave-pair.
__global__ __launch_bounds__(256) void k_egemm(
    const float* __restrict__ emb, const unsigned short* __restrict__ W1b,
    const float* __restrict__ b1, float* __restrict__ E1, int G) {
    int tid = threadIdx.x, lane = tid & 63, wid = tid >> 6;
    int p = lane & 15, q = lane >> 4;
    int wr = wid >> 1, wc = wid & 1;
    int nt = (G + 15) >> 4;
    int t0 = blockIdx.x * 2 + wr;
    if (t0 >= nt) return;

    size_t rc = (size_t)min(t0 * 16 + p, G - 1) * 128;
    float4 xv[8];
#pragma unroll
    for (int kk = 0; kk < 4; ++kk) {
        xv[2 * kk]     = *(const float4*)(emb + rc + kk * 32 + q * 8);
        xv[2 * kk + 1] = *(const float4*)(emb + rc + kk * 32 + q * 8 + 4);
    }
    short8 bfr[4][4];
#pragma unroll
    for (int t = 0; t < 4; ++t)
#pragma unroll
        for (int kk = 0; kk < 4; ++kk)
            bfr[t][kk] = *(const short8*)&W1b[(size_t)(wc * 64 + t * 16 + p) * 128 + kk * 32 + q * 8];
    float b1v[4];
#pragma unroll
    for (int t = 0; t < 4; ++t) b1v[t] = b1[wc * 64 + t * 16 + p];

    short8 afr[4];
#pragma unroll
    for (int kk = 0; kk < 4; ++kk) afr[kk] = pack8(xv[2 * kk], xv[2 * kk + 1]);
    f32x4 acc[4];
#pragma unroll
    for (int t = 0; t < 4; ++t) acc[t] = f32x4{0.f, 0.f, 0.f, 0.f};
#pragma unroll
    for (int t = 0; t < 4; ++t)
#pragma unroll
        for (int kk = 0; kk < 4; ++kk)
            acc[t] = __builtin_amdgcn_mfma_f32_16x16x32_bf16(afr[kk], bfr[t][kk], acc[t], 0, 0, 0);
#pragma unroll
    for (int t = 0; t < 4; ++t) {
        int colb = wc * 64 + t * 16 + p;
#pragma unroll
        for (int rg = 0; rg < 4; ++rg) {
            int rr = t0 * 16 + q * 4 + rg;
            if (rr < G) E1[(size_t)rr * 128 + colb] = acc[t][rg] + b1v[t];
        }
    }
}

// x_out = x @ W1a^T + E1[gid]  (E1 already includes b1).
// PERSISTENT wave-pairs: grid-stride over 16-row tiles, W fragments loaded once,
// 1-tile-deep register prefetch (xc/xn ping-pong, static indices), next gid
// issued first each iter (heads the E1-gather chain). launch_bounds(256,1)
// lifts the VGPR cap so the ~180-reg working set stays resident (no spill).
__global__ __launch_bounds__(256, 1) void k_xgemm(
    const float* __restrict__ x, const unsigned short* __restrict__ W1a,
    const int* __restrict__ gid, const float* __restrict__ E1,
    float* __restrict__ out, int N) {
    int tid = threadIdx.x, lane = tid & 63, wid = tid >> 6;
    int p = lane & 15, q = lane >> 4;
    int wr = wid >> 1, wc = wid & 1;
    int nt = (N + 15) >> 4;
    int step = gridDim.x * 2;
    int t0 = blockIdx.x * 2 + wr;
    if (t0 >= nt) return;

    short8 bfr[4][4];                    // W resident for the wave's lifetime
#pragma unroll
    for (int t = 0; t < 4; ++t)
#pragma unroll
        for (int kk = 0; kk < 4; ++kk)
            bfr[t][kk] = *(const short8*)&W1a[(size_t)(wc * 64 + t * 16 + p) * 128 + kk * 32 + q * 8];

    // preload tile t0: gid + x
    int rowc = min(t0 * 16 + p, N - 1);
    int gc = gid[rowc];
    float4 xc[8];
    {
        size_t rc = (size_t)rowc * 128;
#pragma unroll
        for (int kk = 0; kk < 4; ++kk) {
            xc[2 * kk]     = *(const float4*)(x + rc + kk * 32 + q * 8);
            xc[2 * kk + 1] = *(const float4*)(x + rc + kk * 32 + q * 8 + 4);
        }
    }

    for (;;) {
        int t1 = t0 + step;
        bool more = (t1 < nt);
        int gn = 0;
        float4 xn[8];
        if (more) {
            int rown = min(t1 * 16 + p, N - 1);
            gn = gid[rown];                       // issue first: heads next E1 chain
            size_t rn = (size_t)rown * 128;
#pragma unroll
            for (int kk = 0; kk < 4; ++kk) {
                xn[2 * kk]     = *(const float4*)(x + rn + kk * 32 + q * 8);
                xn[2 * kk + 1] = *(const float4*)(x + rn + kk * 32 + q * 8 + 4);
            }
        }

        // E1 gather for current tile (gc loaded last iter -> address ready)
        int g4[4];
#pragma unroll
        for (int rg = 0; rg < 4; ++rg) g4[rg] = __shfl(gc, q * 4 + rg);
        float ev[4][4];
#pragma unroll
        for (int t = 0; t < 4; ++t) {
            int colb = wc * 64 + t * 16 + p;
#pragma unroll
            for (int rg = 0; rg < 4; ++rg)
                ev[t][rg] = E1[(size_t)g4[rg] * 128 + colb];
        }

        short8 afr[4];
#pragma unroll
        for (int kk = 0; kk < 4; ++kk) afr[kk] = pack8(xc[2 * kk], xc[2 * kk + 1]);
        f32x4 acc[4];
#pragma unroll
        for (int t = 0; t < 4; ++t) acc[t] = f32x4{0.f, 0.f, 0.f, 0.f};
#pragma unroll
        for (int t = 0; t < 4; ++t)
#pragma unroll
            for (int kk = 0; kk < 4; ++kk)
                acc[t] = __builtin_amdgcn_mfma_f32_16x16x32_bf16(afr[kk], bfr[t][kk], acc[t], 0, 0, 0);

#pragma unroll
        for (int t = 0; t < 4; ++t) {
            int colb = wc * 64 + t * 16 + p;
#pragma unroll
            for (int rg = 0; rg < 4; ++rg) {
                int rr = t0 * 16 + q * 4 + rg;
                if (rr < N) out[(size_t)rr * 128 + colb] = acc[t][rg] + ev[t][rg];
            }
        }
        if (!more) break;
        gc = gn;
#pragma unroll
        for (int i = 0; i < 8; ++i) xc[i] = xn[i];
        t0 = t1;
    }
}

// imputed_out = emb @ W2a^T + imps @ W2b^T + b2. One-shot tile per wave-pair.
__global__ __launch_bounds__(256) void k_igemm(
    const float* __restrict__ emb, const unsigned short* __restrict__ imps,
    const unsigned short* __restrict__ W2a, const unsigned short* __restrict__ W2b,
    const float* __restrict__ b2, float* __restrict__ out2, int G) {
    int tid = threadIdx.x, lane = tid & 63, wid = tid >> 6;
    int p = lane & 15, q = lane >> 4;
    int wr = wid >> 1, wc = wid & 1;
    int nt = (G + 15) >> 4;
    int t0 = blockIdx.x * 2 + wr;
    if (t0 >= nt) return;

    int rowc = min(t0 * 16 + p, G - 1);
    size_t rc = (size_t)rowc * 128;
    float4 xv[8];
    short8 ia[4];
#pragma unroll
    for (int kk = 0; kk < 4; ++kk) {
        xv[2 * kk]     = *(const float4*)(emb + rc + kk * 32 + q * 8);
        xv[2 * kk + 1] = *(const float4*)(emb + rc + kk * 32 + q * 8 + 4);
        ia[kk] = *(const short8*)&imps[rc + kk * 32 + q * 8];
    }
    short8 bfrA[4][4], bfrB[4][4];
#pragma unroll
    for (int t = 0; t < 4; ++t)
#pragma unroll
        for (int kk = 0; kk < 4; ++kk) {
            bfrA[t][kk] = *(const short8*)&W2a[(size_t)(wc * 64 + t * 16 + p) * 128 + kk * 32 + q * 8];
            bfrB[t][kk] = *(const short8*)&W2b[(size_t)(wc * 64 + t * 16 + p) * 128 + kk * 32 + q * 8];
        }
    float b2v[4];
#pragma unroll
    for (int t = 0; t < 4; ++t) b2v[t] = b2[wc * 64 + t * 16 + p];

    f32x4 acc[4];
#pragma unroll
    for (int t = 0; t < 4; ++t) acc[t] = f32x4{0.f, 0.f, 0.f, 0.f};
#pragma unroll
    for (int kk = 0; kk < 4; ++kk) {
        short8 ae = pack8(xv[2 * kk], xv[2 * kk + 1]);
#pragma unroll
        for (int t = 0; t < 4; ++t) {
            acc[t] = __builtin_amdgcn_mfma_f32_16x16x32_bf16(ae, bfrA[t][kk], acc[t], 0, 0, 0);
            acc[t] = __builtin_amdgcn_mfma_f32_16x16x32_bf16(ia[kk], bfrB[t][kk], acc[t], 0, 0, 0);
        }
    }
#pragma unroll
    for (int t = 0; t < 4; ++t) {
        int colb = wc * 64 + t * 16 + p;
#pragma unroll
        for (int rg = 0; rg < 4; ++rg) {
            int rr = t0 * 16 + q * 4 + rg;
            if (rr < G) out2[(size_t)rr * 128 + colb] = acc[t][rg] + b2v[t];
        }
    }
}

extern "C" void kernel_launch(void* const* d_in, const int* in_sizes, int n_in,
                              void* d_out, int out_size, void* d_ws, size_t ws_size,
                              hipStream_t stream) {
    const float* x   = (const float*)d_in[0];
    const float* emb = (const float*)d_in[1];
    const float* W1  = (const float*)d_in[2];
    const float* b1  = (const float*)d_in[3];
    const float* W2  = (const float*)d_in[4];
    const float* b2  = (const float*)d_in[5];
    const int*   ids = (const int*)d_in[6];
    const int H = 128;
    const int N = in_sizes[6];
    const int G = in_sizes[1] / H;

    float* out  = (float*)d_out;
    float* out2 = out + (size_t)N * H;
    float* E1   = out2;  // E1 scratch lives in imputed_out region (overwritten by k_igemm last)

    char* ws = (char*)d_ws;
    size_t off = 0;
    int*   cum    = (int*)(ws + off);   off += (size_t)G * 4;
    size_t zbytes = off;                              // zero region: cum only
    off = (off + 255) & ~(size_t)255;
    int* bsum   = (int*)(ws + off); off += 64 * 4;          off = (off + 255) & ~(size_t)255;
    int* gid    = (int*)(ws + off); off += (size_t)N * 4;   off = (off + 255) & ~(size_t)255;
    int* gstart = (int*)(ws + off); off += (size_t)(G + 1) * 4; off = (off + 255) & ~(size_t)255;
    int* ngr    = (int*)(ws + off); off += 256;
    unsigned short* W1a = (unsigned short*)(ws + off); off += (size_t)H * H * 2;
    unsigned short* W1b = (unsigned short*)(ws + off); off += (size_t)H * H * 2;
    unsigned short* W2a = (unsigned short*)(ws + off); off += (size_t)H * H * 2;
    unsigned short* W2b = (unsigned short*)(ws + off); off += (size_t)H * H * 2;
    unsigned short* imps = (unsigned short*)(ws + off); off += (size_t)G * H * 2;

    int n16 = (int)((zbytes + 15) / 16);
    int nb = (G + 1023) >> 10;
    int ntG = (G + 15) >> 4;
    k_zero<<<(n16 + 255) / 256, 256, 0, stream>>>((uint4*)ws, n16);
    k_convw<<<H, 256, 0, stream>>>(W1, W2, W1a, W1b, W2a, W2b);
    k_mark<<<(N + 255) / 256, 256, 0, stream>>>(ids, cum, N);
    k_scan1<<<nb, 256, 0, stream>>>(cum, bsum, G);
    k_scan2<<<1, 64, 0, stream>>>(bsum, nb);
    k_gid<<<(N + 255) / 256, 256, 0, stream>>>(ids, cum, bsum, gid, gstart, ngr, N);
    k_gsum<<<(G + 3) / 4, 256, 0, stream>>>(x, emb, gstart, ngr, imps, G);
    k_egemm<<<(ntG + 1) / 2, 256, 0, stream>>>(emb, W1b, b1, E1, G);
    k_xgemm<<<512, 256, 0, stream>>>(x, W1a, gid, E1, out, N);
    k_igemm<<<(ntG + 1) / 2, 256, 0, stream>>>(emb, imps, W2a, W2b, b2, out2, G);
}

// Round 7
// 285.811 us; speedup vs baseline: 2.5914x; 1.0418x over previous
//
#include <hip/hip_runtime.h>

typedef __attribute__((ext_vector_type(8))) short short8;
typedef __attribute__((ext_vector_type(4))) float f32x4;

static __device__ __forceinline__ unsigned short f2bf(float f) {
    union { float f; unsigned int u; } v; v.f = f;
    unsigned int r = v.u + 0x7fffu + ((v.u >> 16) & 1u);  // RNE
    return (unsigned short)(r >> 16);
}

static __device__ __forceinline__ short8 pack8(float4 a, float4 b) {
    short8 r;
    r[0] = (short)f2bf(a.x); r[1] = (short)f2bf(a.y);
    r[2] = (short)f2bf(a.z); r[3] = (short)f2bf(a.w);
    r[4] = (short)f2bf(b.x); r[5] = (short)f2bf(b.y);
    r[6] = (short)f2bf(b.z); r[7] = (short)f2bf(b.w);
    return r;
}

__global__ void k_zero(uint4* p, int n16) {
    int i = blockIdx.x * blockDim.x + threadIdx.x;
    if (i < n16) p[i] = uint4{0u, 0u, 0u, 0u};
}

// W1,W2 (f32 [128][256]) -> 4 bf16 [128][128] row-major (row j = output col j)
__global__ void k_convw(const float* __restrict__ W1, const float* __restrict__ W2,
                        unsigned short* W1a, unsigned short* W1b,
                        unsigned short* W2a, unsigned short* W2b) {
    int j = blockIdx.x;
    int k = threadIdx.x;
    float w1 = W1[j * 256 + k], w2 = W2[j * 256 + k];
    if (k < 128) { W1a[j * 128 + k] = f2bf(w1); W2a[j * 128 + k] = f2bf(w2); }
    else         { W1b[j * 128 + k - 128] = f2bf(w1); W2b[j * 128 + k - 128] = f2bf(w2); }
}

__global__ void k_mark(const int* __restrict__ ids, int* __restrict__ cum, int n) {
    int i = blockIdx.x * blockDim.x + threadIdx.x;
    if (i < n) cum[ids[i]] = 1;
}

// 2-level scan: per-block inclusive scan of 1024 ints + block sums
__global__ __launch_bounds__(256) void k_scan1(int* __restrict__ cum, int* __restrict__ bsum, int G) {
    __shared__ int ws[4];
    int tid = threadIdx.x;
    int base = blockIdx.x * 1024 + tid * 4;
    int a0 = 0, a1 = 0, a2 = 0, a3 = 0;
    if (base + 0 < G) a0 = cum[base + 0];
    if (base + 1 < G) a1 = cum[base + 1];
    if (base + 2 < G) a2 = cum[base + 2];
    if (base + 3 < G) a3 = cum[base + 3];
    int s = a0 + a1 + a2 + a3;
    int lane = tid & 63;
    int v = s;
#pragma unroll
    for (int off = 1; off < 64; off <<= 1) {
        int u = __shfl_up(v, off, 64);
        if (lane >= off) v += u;
    }
    if (lane == 63) ws[tid >> 6] = v;
    __syncthreads();
    int wof = 0;
    for (int w = 0; w < (tid >> 6); ++w) wof += ws[w];
    int excl = wof + v - s;
    int r0 = excl + a0, r1 = r0 + a1, r2 = r1 + a2, r3 = r2 + a3;
    if (base + 0 < G) cum[base + 0] = r0;
    if (base + 1 < G) cum[base + 1] = r1;
    if (base + 2 < G) cum[base + 2] = r2;
    if (base + 3 < G) cum[base + 3] = r3;
    if (tid == 255) bsum[blockIdx.x] = excl + s;
}

__global__ void k_scan2(int* __restrict__ bsum, int nb) {
    int t = threadIdx.x;  // 64 threads, nb <= 64
    int v = (t < nb) ? bsum[t] : 0;
#pragma unroll
    for (int off = 1; off < 64; off <<= 1) {
        int u = __shfl_up(v, off, 64);
        if (t >= off) v += u;
    }
    if (t < nb) bsum[t] = v;
}

__global__ void k_gid(const int* __restrict__ ids, const int* __restrict__ cum,
                      const int* __restrict__ bsum, int* __restrict__ gid,
                      int* __restrict__ gstart, int* __restrict__ ngr, int n) {
    int i = blockIdx.x * blockDim.x + threadIdx.x;
    if (i >= n) return;
    int v = ids[i];
    int blk = v >> 10;
    int g = cum[v] + (blk ? bsum[blk - 1] : 0) - 1;
    gid[i] = g;
    if (i == 0 || ids[i - 1] != v) gstart[g] = i;
    if (i == n - 1) { gstart[g + 1] = n; *ngr = g + 1; }
}

// imp_second (bf16) per group: one WAVE per group, rows contiguous (sorted ids).
// 4-row chunked software pipeline: next 4 rows in flight (2KB/wave) while
// summing current 4 -> 32 waves/CU x 2KB = 64KB/CU in flight -> HBM-bound.
// n is wave-uniform -> guards are scalar branches, no divergence.
__global__ __launch_bounds__(256) void k_gsum(
    const float* __restrict__ x, const float* __restrict__ emb,
    const int* __restrict__ gstart, const int* __restrict__ ngr,
    unsigned short* __restrict__ imps, int G) {
    int w = blockIdx.x * 4 + (threadIdx.x >> 6);   // wave id = group slot
    int lane = threadIdx.x & 63;
    if (w >= G) return;
    int ng = *ngr;
    float2 m;
    if (w < ng - 1) {
        int a = gstart[w], b = gstart[w + 1];
        int n = b - a;
        const float* px = x + (size_t)a * 128 + lane * 2;
        float2 c0, c1, c2, c3, n0, n1, n2, n3;
        c0 = *(const float2*)(px);
        c1 = *(const float2*)(px + (size_t)min(1, n - 1) * 128);
        c2 = *(const float2*)(px + (size_t)min(2, n - 1) * 128);
        c3 = *(const float2*)(px + (size_t)min(3, n - 1) * 128);
        float sx = 0.f, sy = 0.f;
        for (int base = 0; base < n; base += 4) {
            if (base + 4 < n) {                       // prefetch next chunk (clamped)
                n0 = *(const float2*)(px + (size_t)(base + 4) * 128);
                n1 = *(const float2*)(px + (size_t)min(base + 5, n - 1) * 128);
                n2 = *(const float2*)(px + (size_t)min(base + 6, n - 1) * 128);
                n3 = *(const float2*)(px + (size_t)min(base + 7, n - 1) * 128);
            }
            sx += c0.x; sy += c0.y;
            if (base + 1 < n) { sx += c1.x; sy += c1.y; }
            if (base + 2 < n) { sx += c2.x; sy += c2.y; }
            if (base + 3 < n) { sx += c3.x; sy += c3.y; }
            c0 = n0; c1 = n1; c2 = n2; c3 = n3;
        }
        float inv = 1.0f / (float)n;
        m.x = sx * inv; m.y = sy * inv;
    } else {
        m = *(const float2*)(emb + (size_t)w * 128 + lane * 2);
    }
    unsigned int pk = (unsigned int)f2bf(m.x) | ((unsigned int)f2bf(m.y) << 16);
    ((unsigned int*)imps)[(size_t)w * 64 + lane] = pk;
}

// E1 = emb @ W1b^T + b1 (b1 folded). One-shot 16-row tile per wave-pair.
__global__ __launch_bounds__(256) void k_egemm(
    const float* __restrict__ emb, const unsigned short* __restrict__ W1b,
    const float* __restrict__ b1, float* __restrict__ E1, int G) {
    int tid = threadIdx.x, lane = tid & 63, wid = tid >> 6;
    int p = lane & 15, q = lane >> 4;
    int wr = wid >> 1, wc = wid & 1;
    int nt = (G + 15) >> 4;
    int t0 = blockIdx.x * 2 + wr;
    if (t0 >= nt) return;

    size_t rc = (size_t)min(t0 * 16 + p, G - 1) * 128;
    float4 xv[8];
#pragma unroll
    for (int kk = 0; kk < 4; ++kk) {
        xv[2 * kk]     = *(const float4*)(emb + rc + kk * 32 + q * 8);
        xv[2 * kk + 1] = *(const float4*)(emb + rc + kk * 32 + q * 8 + 4);
    }
    short8 bfr[4][4];
#pragma unroll
    for (int t = 0; t < 4; ++t)
#pragma unroll
        for (int kk = 0; kk < 4; ++kk)
            bfr[t][kk] = *(const short8*)&W1b[(size_t)(wc * 64 + t * 16 + p) * 128 + kk * 32 + q * 8];
    float b1v[4];
#pragma unroll
    for (int t = 0; t < 4; ++t) b1v[t] = b1[wc * 64 + t * 16 + p];

    short8 afr[4];
#pragma unroll
    for (int kk = 0; kk < 4; ++kk) afr[kk] = pack8(xv[2 * kk], xv[2 * kk + 1]);
    f32x4 acc[4];
#pragma unroll
    for (int t = 0; t < 4; ++t) acc[t] = f32x4{0.f, 0.f, 0.f, 0.f};
#pragma unroll
    for (int t = 0; t < 4; ++t)
#pragma unroll
        for (int kk = 0; kk < 4; ++kk)
            acc[t] = __builtin_amdgcn_mfma_f32_16x16x32_bf16(afr[kk], bfr[t][kk], acc[t], 0, 0, 0);
#pragma unroll
    for (int t = 0; t < 4; ++t) {
        int colb = wc * 64 + t * 16 + p;
#pragma unroll
        for (int rg = 0; rg < 4; ++rg) {
            int rr = t0 * 16 + q * 4 + rg;
            if (rr < G) E1[(size_t)rr * 128 + colb] = acc[t][rg] + b1v[t];
        }
    }
}

// x_out = x @ W1a^T + E1[gid]  (E1 already includes b1).
// PERSISTENT wave-pairs: grid-stride over 16-row tiles, W fragments loaded once,
// 1-tile-deep register prefetch (xc/xn ping-pong, static indices), next gid
// issued first each iter (heads the E1-gather chain). launch_bounds(256,1)
// lifts the VGPR cap so the ~180-reg working set stays resident (no spill).
__global__ __launch_bounds__(256, 1) void k_xgemm(
    const float* __restrict__ x, const unsigned short* __restrict__ W1a,
    const int* __restrict__ gid, const float* __restrict__ E1,
    float* __restrict__ out, int N) {
    int tid = threadIdx.x, lane = tid & 63, wid = tid >> 6;
    int p = lane & 15, q = lane >> 4;
    int wr = wid >> 1, wc = wid & 1;
    int nt = (N + 15) >> 4;
    int step = gridDim.x * 2;
    int t0 = blockIdx.x * 2 + wr;
    if (t0 >= nt) return;

    short8 bfr[4][4];                    // W resident for the wave's lifetime
#pragma unroll
    for (int t = 0; t < 4; ++t)
#pragma unroll
        for (int kk = 0; kk < 4; ++kk)
            bfr[t][kk] = *(const short8*)&W1a[(size_t)(wc * 64 + t * 16 + p) * 128 + kk * 32 + q * 8];

    // preload tile t0: gid + x
    int rowc = min(t0 * 16 + p, N - 1);
    int gc = gid[rowc];
    float4 xc[8];
    {
        size_t rc = (size_t)rowc * 128;
#pragma unroll
        for (int kk = 0; kk < 4; ++kk) {
            xc[2 * kk]     = *(const float4*)(x + rc + kk * 32 + q * 8);
            xc[2 * kk + 1] = *(const float4*)(x + rc + kk * 32 + q * 8 + 4);
        }
    }

    for (;;) {
        int t1 = t0 + step;
        bool more = (t1 < nt);
        int gn = 0;
        float4 xn[8];
        if (more) {
            int rown = min(t1 * 16 + p, N - 1);
            gn = gid[rown];                       // issue first: heads next E1 chain
            size_t rn = (size_t)rown * 128;
#pragma unroll
            for (int kk = 0; kk < 4; ++kk) {
                xn[2 * kk]     = *(const float4*)(x + rn + kk * 32 + q * 8);
                xn[2 * kk + 1] = *(const float4*)(x + rn + kk * 32 + q * 8 + 4);
            }
        }

        // E1 gather for current tile (gc loaded last iter -> address ready)
        int g4[4];
#pragma unroll
        for (int rg = 0; rg < 4; ++rg) g4[rg] = __shfl(gc, q * 4 + rg);
        float ev[4][4];
#pragma unroll
        for (int t = 0; t < 4; ++t) {
            int colb = wc * 64 + t * 16 + p;
#pragma unroll
            for (int rg = 0; rg < 4; ++rg)
                ev[t][rg] = E1[(size_t)g4[rg] * 128 + colb];
        }

        short8 afr[4];
#pragma unroll
        for (int kk = 0; kk < 4; ++kk) afr[kk] = pack8(xc[2 * kk], xc[2 * kk + 1]);
        f32x4 acc[4];
#pragma unroll
        for (int t = 0; t < 4; ++t) acc[t] = f32x4{0.f, 0.f, 0.f, 0.f};
#pragma unroll
        for (int t = 0; t < 4; ++t)
#pragma unroll
            for (int kk = 0; kk < 4; ++kk)
                acc[t] = __builtin_amdgcn_mfma_f32_16x16x32_bf16(afr[kk], bfr[t][kk], acc[t], 0, 0, 0);

#pragma unroll
        for (int t = 0; t < 4; ++t) {
            int colb = wc * 64 + t * 16 + p;
#pragma unroll
            for (int rg = 0; rg < 4; ++rg) {
                int rr = t0 * 16 + q * 4 + rg;
                if (rr < N) out[(size_t)rr * 128 + colb] = acc[t][rg] + ev[t][rg];
            }
        }
        if (!more) break;
        gc = gn;
#pragma unroll
        for (int i = 0; i < 8; ++i) xc[i] = xn[i];
        t0 = t1;
    }
}

// imputed_out = emb @ W2a^T + imps @ W2b^T + b2. One-shot tile per wave-pair.
__global__ __launch_bounds__(256) void k_igemm(
    const float* __restrict__ emb, const unsigned short* __restrict__ imps,
    const unsigned short* __restrict__ W2a, const unsigned short* __restrict__ W2b,
    const float* __restrict__ b2, float* __restrict__ out2, int G) {
    int tid = threadIdx.x, lane = tid & 63, wid = tid >> 6;
    int p = lane & 15, q = lane >> 4;
    int wr = wid >> 1, wc = wid & 1;
    int nt = (G + 15) >> 4;
    int t0 = blockIdx.x * 2 + wr;
    if (t0 >= nt) return;

    int rowc = min(t0 * 16 + p, G - 1);
    size_t rc = (size_t)rowc * 128;
    float4 xv[8];
    short8 ia[4];
#pragma unroll
    for (int kk = 0; kk < 4; ++kk) {
        xv[2 * kk]     = *(const float4*)(emb + rc + kk * 32 + q * 8);
        xv[2 * kk + 1] = *(const float4*)(emb + rc + kk * 32 + q * 8 + 4);
        ia[kk] = *(const short8*)&imps[rc + kk * 32 + q * 8];
    }
    short8 bfrA[4][4], bfrB[4][4];
#pragma unroll
    for (int t = 0; t < 4; ++t)
#pragma unroll
        for (int kk = 0; kk < 4; ++kk) {
            bfrA[t][kk] = *(const short8*)&W2a[(size_t)(wc * 64 + t * 16 + p) * 128 + kk * 32 + q * 8];
            bfrB[t][kk] = *(const short8*)&W2b[(size_t)(wc * 64 + t * 16 + p) * 128 + kk * 32 + q * 8];
        }
    float b2v[4];
#pragma unroll
    for (int t = 0; t < 4; ++t) b2v[t] = b2[wc * 64 + t * 16 + p];

    f32x4 acc[4];
#pragma unroll
    for (int t = 0; t < 4; ++t) acc[t] = f32x4{0.f, 0.f, 0.f, 0.f};
#pragma unroll
    for (int kk = 0; kk < 4; ++kk) {
        short8 ae = pack8(xv[2 * kk], xv[2 * kk + 1]);
#pragma unroll
        for (int t = 0; t < 4; ++t) {
            acc[t] = __builtin_amdgcn_mfma_f32_16x16x32_bf16(ae, bfrA[t][kk], acc[t], 0, 0, 0);
            acc[t] = __builtin_amdgcn_mfma_f32_16x16x32_bf16(ia[kk], bfrB[t][kk], acc[t], 0, 0, 0);
        }
    }
#pragma unroll
    for (int t = 0; t < 4; ++t) {
        int colb = wc * 64 + t * 16 + p;
#pragma unroll
        for (int rg = 0; rg < 4; ++rg) {
            int rr = t0 * 16 + q * 4 + rg;
            if (rr < G) out2[(size_t)rr * 128 + colb] = acc[t][rg] + b2v[t];
        }
    }
}

extern "C" void kernel_launch(void* const* d_in, const int* in_sizes, int n_in,
                              void* d_out, int out_size, void* d_ws, size_t ws_size,
                              hipStream_t stream) {
    const float* x   = (const float*)d_in[0];
    const float* emb = (const float*)d_in[1];
    const float* W1  = (const float*)d_in[2];
    const float* b1  = (const float*)d_in[3];
    const float* W2  = (const float*)d_in[4];
    const float* b2  = (const float*)d_in[5];
    const int*   ids = (const int*)d_in[6];
    const int H = 128;
    const int N = in_sizes[6];
    const int G = in_sizes[1] / H;

    float* out  = (float*)d_out;
    float* out2 = out + (size_t)N * H;
    float* E1   = out2;  // E1 scratch lives in imputed_out region (overwritten by k_igemm last)

    char* ws = (char*)d_ws;
    size_t off = 0;
    int*   cum    = (int*)(ws + off);   off += (size_t)G * 4;
    size_t zbytes = off;                              // zero region: cum only
    off = (off + 255) & ~(size_t)255;
    int* bsum   = (int*)(ws + off); off += 64 * 4;          off = (off + 255) & ~(size_t)255;
    int* gid    = (int*)(ws + off); off += (size_t)N * 4;   off = (off + 255) & ~(size_t)255;
    int* gstart = (int*)(ws + off); off += (size_t)(G + 1) * 4; off = (off + 255) & ~(size_t)255;
    int* ngr    = (int*)(ws + off); off += 256;
    unsigned short* W1a = (unsigned short*)(ws + off); off += (size_t)H * H * 2;
    unsigned short* W1b = (unsigned short*)(ws + off); off += (size_t)H * H * 2;
    unsigned short* W2a = (unsigned short*)(ws + off); off += (size_t)H * H * 2;
    unsigned short* W2b = (unsigned short*)(ws + off); off += (size_t)H * H * 2;
    unsigned short* imps = (unsigned short*)(ws + off); off += (size_t)G * H * 2;

    int n16 = (int)((zbytes + 15) / 16);
    int nb = (G + 1023) >> 10;
    int ntG = (G + 15) >> 4;
    k_zero<<<(n16 + 255) / 256, 256, 0, stream>>>((uint4*)ws, n16);
    k_convw<<<H, 256, 0, stream>>>(W1, W2, W1a, W1b, W2a, W2b);
    k_mark<<<(N + 255) / 256, 256, 0, stream>>>(ids, cum, N);
    k_scan1<<<nb, 256, 0, stream>>>(cum, bsum, G);
    k_scan2<<<1, 64, 0, stream>>>(bsum, nb);
    k_gid<<<(N + 255) / 256, 256, 0, stream>>>(ids, cum, bsum, gid, gstart, ngr, N);
    k_gsum<<<(G + 3) / 4, 256, 0, stream>>>(x, emb, gstart, ngr, imps, G);
    k_egemm<<<(ntG + 1) / 2, 256, 0, stream>>>(emb, W1b, b1, E1, G);
    k_xgemm<<<512, 256, 0, stream>>>(x, W1a, gid, E1, out, N);
    k_igemm<<<(ntG + 1) / 2, 256, 0, stream>>>(emb, imps, W2a, W2b, b2, out2, G);
}

// Round 8
// 227.483 us; speedup vs baseline: 3.2558x; 1.2564x over previous
//
#include <hip/hip_runtime.h>

typedef __attribute__((ext_vector_type(8))) short short8;
typedef __attribute__((ext_vector_type(4))) float f32x4;

static __device__ __forceinline__ unsigned short f2bf(float f) {
    union { float f; unsigned int u; } v; v.f = f;
    unsigned int r = v.u + 0x7fffu + ((v.u >> 16) & 1u);  // RNE
    return (unsigned short)(r >> 16);
}

static __device__ __forceinline__ short8 pack8(float4 a, float4 b) {
    short8 r;
    r[0] = (short)f2bf(a.x); r[1] = (short)f2bf(a.y);
    r[2] = (short)f2bf(a.z); r[3] = (short)f2bf(a.w);
    r[4] = (short)f2bf(b.x); r[5] = (short)f2bf(b.y);
    r[6] = (short)f2bf(b.z); r[7] = (short)f2bf(b.w);
    return r;
}

static __device__ __forceinline__ void dma16(const void* g, void* l) {
    __builtin_amdgcn_global_load_lds(
        (const __attribute__((address_space(1))) unsigned int*)g,
        (__attribute__((address_space(3))) unsigned int*)l, 16, 0, 0);
}

static __device__ __forceinline__ float4 lds_rd16(const float* buf, int boff, int sw) {
    return *(const float4*)((const char*)buf + (boff ^ sw));
}

__global__ void k_zero(uint4* p, int n16) {
    int i = blockIdx.x * blockDim.x + threadIdx.x;
    if (i < n16) p[i] = uint4{0u, 0u, 0u, 0u};
}

// Pack W1,W2 (f32 [128][256]) into 4 fragment-ordered bf16 arrays:
// frag f=(wc*4+t)*4+kk, element [f*512 + lane*8 + j] = W[wc*64+t*16+(lane&15)]
// [half*128 + kk*32 + (lane>>4)*8 + j]  -> GEMM bfr loads become contiguous 1KB.
__global__ void k_convw(const float* __restrict__ W1, const float* __restrict__ W2,
                        unsigned short* W1af, unsigned short* W1bf,
                        unsigned short* W2af, unsigned short* W2bf) {
    int T = blockIdx.x * 256 + threadIdx.x;   // 8192 total
    int mat = T >> 11;
    int rem = T & 2047;
    int f = rem >> 6, lane = rem & 63;
    int wc = f >> 4, t = (f >> 2) & 3, kk = f & 3;
    int p = lane & 15, q = lane >> 4;
    int row = wc * 64 + t * 16 + p;
    int col = (mat & 1) * 128 + kk * 32 + q * 8;
    const float* src = (mat < 2 ? W1 : W2) + row * 256 + col;
    unsigned short* dst = (mat == 0 ? W1af : mat == 1 ? W1bf : mat == 2 ? W2af : W2bf);
    short8 v;
#pragma unroll
    for (int j = 0; j < 8; ++j) v[j] = (short)f2bf(src[j]);
    *(short8*)&dst[(size_t)f * 512 + lane * 8] = v;
}

__global__ void k_mark(const int* __restrict__ ids, int* __restrict__ cum, int n) {
    int i = blockIdx.x * blockDim.x + threadIdx.x;
    if (i < n) cum[ids[i]] = 1;
}

// 2-level scan: per-block inclusive scan of 1024 ints + block sums
__global__ __launch_bounds__(256) void k_scan1(int* __restrict__ cum, int* __restrict__ bsum, int G) {
    __shared__ int ws[4];
    int tid = threadIdx.x;
    int base = blockIdx.x * 1024 + tid * 4;
    int a0 = 0, a1 = 0, a2 = 0, a3 = 0;
    if (base + 0 < G) a0 = cum[base + 0];
    if (base + 1 < G) a1 = cum[base + 1];
    if (base + 2 < G) a2 = cum[base + 2];
    if (base + 3 < G) a3 = cum[base + 3];
    int s = a0 + a1 + a2 + a3;
    int lane = tid & 63;
    int v = s;
#pragma unroll
    for (int off = 1; off < 64; off <<= 1) {
        int u = __shfl_up(v, off, 64);
        if (lane >= off) v += u;
    }
    if (lane == 63) ws[tid >> 6] = v;
    __syncthreads();
    int wof = 0;
    for (int w = 0; w < (tid >> 6); ++w) wof += ws[w];
    int excl = wof + v - s;
    int r0 = excl + a0, r1 = r0 + a1, r2 = r1 + a2, r3 = r2 + a3;
    if (base + 0 < G) cum[base + 0] = r0;
    if (base + 1 < G) cum[base + 1] = r1;
    if (base + 2 < G) cum[base + 2] = r2;
    if (base + 3 < G) cum[base + 3] = r3;
    if (tid == 255) bsum[blockIdx.x] = excl + s;
}

__global__ void k_scan2(int* __restrict__ bsum, int nb) {
    int t = threadIdx.x;  // 64 threads, nb <= 64
    int v = (t < nb) ? bsum[t] : 0;
#pragma unroll
    for (int off = 1; off < 64; off <<= 1) {
        int u = __shfl_up(v, off, 64);
        if (t >= off) v += u;
    }
    if (t < nb) bsum[t] = v;
}

__global__ void k_gid(const int* __restrict__ ids, const int* __restrict__ cum,
                      const int* __restrict__ bsum, int* __restrict__ gid,
                      int* __restrict__ gstart, int* __restrict__ ngr, int n) {
    int i = blockIdx.x * blockDim.x + threadIdx.x;
    if (i >= n) return;
    int v = ids[i];
    int blk = v >> 10;
    int g = cum[v] + (blk ? bsum[blk - 1] : 0) - 1;
    gid[i] = g;
    if (i == 0 || ids[i - 1] != v) gstart[g] = i;
    if (i == n - 1) { gstart[g + 1] = n; *ngr = g + 1; }
}

// imp_second (bf16) per group: one WAVE per group (rows contiguous, sorted ids).
// Coalesced float2 loads; 4-row chunked software pipeline.
__global__ __launch_bounds__(256) void k_gsum(
    const float* __restrict__ x, const float* __restrict__ emb,
    const int* __restrict__ gstart, const int* __restrict__ ngr,
    unsigned short* __restrict__ imps, int G) {
    int w = blockIdx.x * 4 + (threadIdx.x >> 6);
    int lane = threadIdx.x & 63;
    if (w >= G) return;
    int ng = *ngr;
    float2 m;
    if (w < ng - 1) {
        int a = gstart[w], b = gstart[w + 1];
        int n = b - a;
        const float* px = x + (size_t)a * 128 + lane * 2;
        float2 c0, c1, c2, c3, n0, n1, n2, n3;
        c0 = *(const float2*)(px);
        c1 = *(const float2*)(px + (size_t)min(1, n - 1) * 128);
        c2 = *(const float2*)(px + (size_t)min(2, n - 1) * 128);
        c3 = *(const float2*)(px + (size_t)min(3, n - 1) * 128);
        float sx = 0.f, sy = 0.f;
        for (int base = 0; base < n; base += 4) {
            if (base + 4 < n) {
                n0 = *(const float2*)(px + (size_t)(base + 4) * 128);
                n1 = *(const float2*)(px + (size_t)min(base + 5, n - 1) * 128);
                n2 = *(const float2*)(px + (size_t)min(base + 6, n - 1) * 128);
                n3 = *(const float2*)(px + (size_t)min(base + 7, n - 1) * 128);
            }
            sx += c0.x; sy += c0.y;
            if (base + 1 < n) { sx += c1.x; sy += c1.y; }
            if (base + 2 < n) { sx += c2.x; sy += c2.y; }
            if (base + 3 < n) { sx += c3.x; sy += c3.y; }
            c0 = n0; c1 = n1; c2 = n2; c3 = n3;
        }
        float inv = 1.0f / (float)n;
        m.x = sx * inv; m.y = sy * inv;
    } else {
        m = *(const float2*)(emb + (size_t)w * 128 + lane * 2);
    }
    unsigned int pk = (unsigned int)f2bf(m.x) | ((unsigned int)f2bf(m.y) << 16);
    ((unsigned int*)imps)[(size_t)w * 64 + lane] = pk;
}

// E1 = emb @ W1b^T + b1. 128-row block, LDS-staged, one barrier.
__global__ __launch_bounds__(256, 2) void k_egemm(
    const float* __restrict__ emb, const unsigned short* __restrict__ Wf,
    const float* __restrict__ b1, float* __restrict__ E1, int G) {
    __shared__ __align__(16) float ebuf[16384];   // 64KB: 128 rows f32
    int tid = threadIdx.x, lane = tid & 63, wid = tid >> 6;
    int p = lane & 15, q = lane >> 4;
    int wr = wid >> 1, wc = wid & 1;
    int row0 = blockIdx.x * 128;

    short8 bfr[4][4];
#pragma unroll
    for (int t = 0; t < 4; ++t)
#pragma unroll
        for (int kk = 0; kk < 4; ++kk)
            bfr[t][kk] = *(const short8*)&Wf[(size_t)((wc * 4 + t) * 4 + kk) * 512 + lane * 8];
    float b1v[4];
#pragma unroll
    for (int t = 0; t < 4; ++t) b1v[t] = b1[wc * 64 + t * 16 + p];

    long long maxb = (long long)G * 512 - 16;
#pragma unroll
    for (int k = 0; k < 16; ++k) {
        int doff = k * 4096 + tid * 16;
        int r = doff >> 9;
        long long s = (long long)(row0 + r) * 512 + (long long)((doff & 511) ^ ((r & 7) << 4));
        s = s < maxb ? s : maxb;
        dma16((const char*)emb + s, (char*)ebuf + doff);
    }
    asm volatile("s_waitcnt vmcnt(0)" ::: "memory");
    __builtin_amdgcn_s_barrier();
    __builtin_amdgcn_sched_barrier(0);

    int sw = (p & 7) << 4;
#pragma unroll
    for (int tt = 0; tt < 4; ++tt) {
        int lr = wr * 64 + tt * 16 + p;
        short8 afr[4];
#pragma unroll
        for (int kk = 0; kk < 4; ++kk) {
            int boff = lr * 512 + kk * 128 + q * 32;
            float4 v0 = lds_rd16(ebuf, boff, sw);
            float4 v1 = lds_rd16(ebuf, boff + 16, sw);
            afr[kk] = pack8(v0, v1);
        }
        f32x4 acc[4];
#pragma unroll
        for (int t = 0; t < 4; ++t) acc[t] = f32x4{0.f, 0.f, 0.f, 0.f};
#pragma unroll
        for (int t = 0; t < 4; ++t)
#pragma unroll
            for (int kk = 0; kk < 4; ++kk)
                acc[t] = __builtin_amdgcn_mfma_f32_16x16x32_bf16(afr[kk], bfr[t][kk], acc[t], 0, 0, 0);
#pragma unroll
        for (int t = 0; t < 4; ++t) {
            int colb = wc * 64 + t * 16 + p;
#pragma unroll
            for (int rg = 0; rg < 4; ++rg) {
                int rr = row0 + wr * 64 + tt * 16 + q * 4 + rg;
                if (rr < G) E1[(size_t)rr * 128 + colb] = acc[t][rg] + b1v[t];
            }
        }
    }
}

// x_out = x @ W1a^T + E1[gid]. 128-row block, LDS-staged x (coalesced DMA +
// XOR swizzle), fragment-ordered W, one barrier, XCD-swizzled blockIdx.
__global__ __launch_bounds__(256, 2) void k_xgemm(
    const float* __restrict__ x, const unsigned short* __restrict__ Wf,
    const int* __restrict__ gid, const float* __restrict__ E1,
    float* __restrict__ out, int N, int nwg) {
    __shared__ __align__(16) float xbuf[16384];   // 64KB: 128 rows f32
    int tid = threadIdx.x, lane = tid & 63, wid = tid >> 6;
    int p = lane & 15, q = lane >> 4;
    int wr = wid >> 1, wc = wid & 1;
    // bijective XCD swizzle (m204)
    int orig = blockIdx.x;
    int qq = nwg >> 3, rr8 = nwg & 7;
    int xcd = orig & 7, idx = orig >> 3;
    int bid = (xcd < rr8 ? xcd * (qq + 1) : rr8 * (qq + 1) + (xcd - rr8) * qq) + idx;
    int row0 = bid * 128;

    short8 bfr[4][4];
#pragma unroll
    for (int t = 0; t < 4; ++t)
#pragma unroll
        for (int kk = 0; kk < 4; ++kk)
            bfr[t][kk] = *(const short8*)&Wf[(size_t)((wc * 4 + t) * 4 + kk) * 512 + lane * 8];

    int gt0 = gid[min(row0 + wr * 64 + 0 * 16 + p, N - 1)];
    int gt1 = gid[min(row0 + wr * 64 + 1 * 16 + p, N - 1)];
    int gt2 = gid[min(row0 + wr * 64 + 2 * 16 + p, N - 1)];
    int gt3 = gid[min(row0 + wr * 64 + 3 * 16 + p, N - 1)];

    long long maxb = (long long)N * 512 - 16;
#pragma unroll
    for (int k = 0; k < 16; ++k) {
        int doff = k * 4096 + tid * 16;
        int r = doff >> 9;
        long long s = (long long)(row0 + r) * 512 + (long long)((doff & 511) ^ ((r & 7) << 4));
        s = s < maxb ? s : maxb;
        dma16((const char*)x + s, (char*)xbuf + doff);
    }
    asm volatile("s_waitcnt vmcnt(0)" ::: "memory");
    __builtin_amdgcn_s_barrier();
    __builtin_amdgcn_sched_barrier(0);

    int sw = (p & 7) << 4;
#pragma unroll
    for (int tt = 0; tt < 4; ++tt) {
        int gt = (tt == 0) ? gt0 : (tt == 1) ? gt1 : (tt == 2) ? gt2 : gt3;
        int lr = wr * 64 + tt * 16 + p;
        short8 afr[4];
#pragma unroll
        for (int kk = 0; kk < 4; ++kk) {
            int boff = lr * 512 + kk * 128 + q * 32;
            float4 v0 = lds_rd16(xbuf, boff, sw);
            float4 v1 = lds_rd16(xbuf, boff + 16, sw);
            afr[kk] = pack8(v0, v1);
        }
        int g4[4];
#pragma unroll
        for (int rg = 0; rg < 4; ++rg) g4[rg] = __shfl(gt, q * 4 + rg);
        float ev[4][4];
#pragma unroll
        for (int t = 0; t < 4; ++t) {
            int colb = wc * 64 + t * 16 + p;
#pragma unroll
            for (int rg = 0; rg < 4; ++rg)
                ev[t][rg] = E1[(size_t)g4[rg] * 128 + colb];
        }
        f32x4 acc[4];
#pragma unroll
        for (int t = 0; t < 4; ++t) acc[t] = f32x4{0.f, 0.f, 0.f, 0.f};
#pragma unroll
        for (int t = 0; t < 4; ++t)
#pragma unroll
            for (int kk = 0; kk < 4; ++kk)
                acc[t] = __builtin_amdgcn_mfma_f32_16x16x32_bf16(afr[kk], bfr[t][kk], acc[t], 0, 0, 0);
#pragma unroll
        for (int t = 0; t < 4; ++t) {
            int colb = wc * 64 + t * 16 + p;
#pragma unroll
            for (int rg = 0; rg < 4; ++rg) {
                int rr = row0 + wr * 64 + tt * 16 + q * 4 + rg;
                if (rr < N) out[(size_t)rr * 128 + colb] = acc[t][rg] + ev[t][rg];
            }
        }
    }
}

// imputed_out = emb @ W2a^T + imps @ W2b^T + b2. 64-row block, LDS-staged.
__global__ __launch_bounds__(256, 2) void k_igemm(
    const float* __restrict__ emb, const unsigned short* __restrict__ imps,
    const unsigned short* __restrict__ Waf, const unsigned short* __restrict__ Wbf,
    const float* __restrict__ b2, float* __restrict__ out2, int G) {
    __shared__ __align__(16) float ebuf[8192];            // 32KB: 64 rows f32
    __shared__ __align__(16) unsigned short ibuf[8192];   // 16KB: 64 rows bf16
    int tid = threadIdx.x, lane = tid & 63, wid = tid >> 6;
    int p = lane & 15, q = lane >> 4;
    int wr = wid >> 1, wc = wid & 1;
    int row0 = blockIdx.x * 64;

    short8 bfrA[4][4], bfrB[4][4];
#pragma unroll
    for (int t = 0; t < 4; ++t)
#pragma unroll
        for (int kk = 0; kk < 4; ++kk) {
            bfrA[t][kk] = *(const short8*)&Waf[(size_t)((wc * 4 + t) * 4 + kk) * 512 + lane * 8];
            bfrB[t][kk] = *(const short8*)&Wbf[(size_t)((wc * 4 + t) * 4 + kk) * 512 + lane * 8];
        }
    float b2v[4];
#pragma unroll
    for (int t = 0; t < 4; ++t) b2v[t] = b2[wc * 64 + t * 16 + p];

    long long maxe = (long long)G * 512 - 16;
    long long maxi = (long long)G * 256 - 16;
#pragma unroll
    for (int k = 0; k < 8; ++k) {
        int doff = k * 4096 + tid * 16;
        int r = doff >> 9;
        long long s = (long long)(row0 + r) * 512 + (long long)((doff & 511) ^ ((r & 7) << 4));
        s = s < maxe ? s : maxe;
        dma16((const char*)emb + s, (char*)ebuf + doff);
    }
#pragma unroll
    for (int k = 0; k < 4; ++k) {
        int doff = k * 4096 + tid * 16;
        int r = doff >> 8;
        long long s = (long long)(row0 + r) * 256 + (long long)((doff & 255) ^ ((r & 7) << 4));
        s = s < maxi ? s : maxi;
        dma16((const char*)imps + s, (char*)ibuf + doff);
    }
    asm volatile("s_waitcnt vmcnt(0)" ::: "memory");
    __builtin_amdgcn_s_barrier();
    __builtin_amdgcn_sched_barrier(0);

    int sw = (p & 7) << 4;
#pragma unroll
    for (int tt = 0; tt < 2; ++tt) {
        int lr = wr * 32 + tt * 16 + p;
        short8 ae[4], ia[4];
#pragma unroll
        for (int kk = 0; kk < 4; ++kk) {
            int boff = lr * 512 + kk * 128 + q * 32;
            float4 v0 = lds_rd16(ebuf, boff, sw);
            float4 v1 = lds_rd16(ebuf, boff + 16, sw);
            ae[kk] = pack8(v0, v1);
            int boff2 = lr * 256 + ((kk * 64 + q * 16) ^ sw);
            ia[kk] = *(const short8*)((const char*)ibuf + boff2);
        }
        f32x4 acc[4];
#pragma unroll
        for (int t = 0; t < 4; ++t) acc[t] = f32x4{0.f, 0.f, 0.f, 0.f};
#pragma unroll
        for (int kk = 0; kk < 4; ++kk)
#pragma unroll
            for (int t = 0; t < 4; ++t) {
                acc[t] = __builtin_amdgcn_mfma_f32_16x16x32_bf16(ae[kk], bfrA[t][kk], acc[t], 0, 0, 0);
                acc[t] = __builtin_amdgcn_mfma_f32_16x16x32_bf16(ia[kk], bfrB[t][kk], acc[t], 0, 0, 0);
            }
#pragma unroll
        for (int t = 0; t < 4; ++t) {
            int colb = wc * 64 + t * 16 + p;
#pragma unroll
            for (int rg = 0; rg < 4; ++rg) {
                int rr = row0 + wr * 32 + tt * 16 + q * 4 + rg;
                if (rr < G) out2[(size_t)rr * 128 + colb] = acc[t][rg] + b2v[t];
            }
        }
    }
}

extern "C" void kernel_launch(void* const* d_in, const int* in_sizes, int n_in,
                              void* d_out, int out_size, void* d_ws, size_t ws_size,
                              hipStream_t stream) {
    const float* x   = (const float*)d_in[0];
    const float* emb = (const float*)d_in[1];
    const float* W1  = (const float*)d_in[2];
    const float* b1  = (const float*)d_in[3];
    const float* W2  = (const float*)d_in[4];
    const float* b2  = (const float*)d_in[5];
    const int*   ids = (const int*)d_in[6];
    const int H = 128;
    const int N = in_sizes[6];
    const int G = in_sizes[1] / H;

    float* out  = (float*)d_out;
    float* out2 = out + (size_t)N * H;
    float* E1   = out2;  // E1 scratch lives in imputed_out region (overwritten by k_igemm last)

    char* ws = (char*)d_ws;
    size_t off = 0;
    int*   cum    = (int*)(ws + off);   off += (size_t)G * 4;
    size_t zbytes = off;                              // zero region: cum only
    off = (off + 255) & ~(size_t)255;
    int* bsum   = (int*)(ws + off); off += 64 * 4;          off = (off + 255) & ~(size_t)255;
    int* gid    = (int*)(ws + off); off += (size_t)N * 4;   off = (off + 255) & ~(size_t)255;
    int* gstart = (int*)(ws + off); off += (size_t)(G + 1) * 4; off = (off + 255) & ~(size_t)255;
    int* ngr    = (int*)(ws + off); off += 256;
    unsigned short* W1af = (unsigned short*)(ws + off); off += (size_t)H * H * 2;
    unsigned short* W1bf = (unsigned short*)(ws + off); off += (size_t)H * H * 2;
    unsigned short* W2af = (unsigned short*)(ws + off); off += (size_t)H * H * 2;
    unsigned short* W2bf = (unsigned short*)(ws + off); off += (size_t)H * H * 2;
    unsigned short* imps = (unsigned short*)(ws + off); off += (size_t)G * H * 2;

    int n16 = (int)((zbytes + 15) / 16);
    int nb = (G + 1023) >> 10;
    int nwgX = (N + 127) >> 7;
    int nwgE = (G + 127) >> 7;
    int nwgI = (G + 63) >> 6;
    k_zero<<<(n16 + 255) / 256, 256, 0, stream>>>((uint4*)ws, n16);
    k_convw<<<32, 256, 0, stream>>>(W1, W2, W1af, W1bf, W2af, W2bf);
    k_mark<<<(N + 255) / 256, 256, 0, stream>>>(ids, cum, N);
    k_scan1<<<nb, 256, 0, stream>>>(cum, bsum, G);
    k_scan2<<<1, 64, 0, stream>>>(bsum, nb);
    k_gid<<<(N + 255) / 256, 256, 0, stream>>>(ids, cum, bsum, gid, gstart, ngr, N);
    k_gsum<<<(G + 3) / 4, 256, 0, stream>>>(x, emb, gstart, ngr, imps, G);
    k_egemm<<<nwgE, 256, 0, stream>>>(emb, W1bf, b1, E1, G);
    k_xgemm<<<nwgX, 256, 0, stream>>>(x, W1af, gid, E1, out, N, nwgX);
    k_igemm<<<nwgI, 256, 0, stream>>>(emb, imps, W2af, W2bf, b2, out2, G);
}

// Round 9
// 219.099 us; speedup vs baseline: 3.3804x; 1.0383x over previous
//
#include <hip/hip_runtime.h>

typedef __attribute__((ext_vector_type(8))) short short8;
typedef __attribute__((ext_vector_type(4))) float f32x4;

static __device__ __forceinline__ unsigned short f2bf(float f) {
    union { float f; unsigned int u; } v; v.f = f;
    unsigned int r = v.u + 0x7fffu + ((v.u >> 16) & 1u);  // RNE
    return (unsigned short)(r >> 16);
}

static __device__ __forceinline__ short8 pack8(float4 a, float4 b) {
    short8 r;
    r[0] = (short)f2bf(a.x); r[1] = (short)f2bf(a.y);
    r[2] = (short)f2bf(a.z); r[3] = (short)f2bf(a.w);
    r[4] = (short)f2bf(b.x); r[5] = (short)f2bf(b.y);
    r[6] = (short)f2bf(b.z); r[7] = (short)f2bf(b.w);
    return r;
}

static __device__ __forceinline__ void dma16(const void* g, void* l) {
    __builtin_amdgcn_global_load_lds(
        (const __attribute__((address_space(1))) unsigned int*)g,
        (__attribute__((address_space(3))) unsigned int*)l, 16, 0, 0);
}

static __device__ __forceinline__ float4 lds_rd16(const float* buf, int boff, int sw) {
    return *(const float4*)((const char*)buf + (boff ^ sw));
}

__global__ void k_zero(uint4* p, int n16) {
    int i = blockIdx.x * blockDim.x + threadIdx.x;
    if (i < n16) p[i] = uint4{0u, 0u, 0u, 0u};
}

// Pack W1,W2 (f32 [128][256]) into 4 fragment-ordered bf16 arrays:
// frag f=(wc*4+t)*4+kk, element [f*512 + lane*8 + j] -> contiguous 1KB bfr loads.
__global__ void k_convw(const float* __restrict__ W1, const float* __restrict__ W2,
                        unsigned short* W1af, unsigned short* W1bf,
                        unsigned short* W2af, unsigned short* W2bf) {
    int T = blockIdx.x * 256 + threadIdx.x;   // 8192 total
    int mat = T >> 11;
    int rem = T & 2047;
    int f = rem >> 6, lane = rem & 63;
    int wc = f >> 4, t = (f >> 2) & 3, kk = f & 3;
    int p = lane & 15, q = lane >> 4;
    int row = wc * 64 + t * 16 + p;
    int col = (mat & 1) * 128 + kk * 32 + q * 8;
    const float* src = (mat < 2 ? W1 : W2) + row * 256 + col;
    unsigned short* dst = (mat == 0 ? W1af : mat == 1 ? W1bf : mat == 2 ? W2af : W2bf);
    short8 v;
#pragma unroll
    for (int j = 0; j < 8; ++j) v[j] = (short)f2bf(src[j]);
    *(short8*)&dst[(size_t)f * 512 + lane * 8] = v;
}

__global__ void k_mark(const int* __restrict__ ids, int* __restrict__ cum, int n) {
    int i = blockIdx.x * blockDim.x + threadIdx.x;
    if (i < n) cum[ids[i]] = 1;
}

// 2-level scan: per-block inclusive scan of 1024 ints + block sums
__global__ __launch_bounds__(256) void k_scan1(int* __restrict__ cum, int* __restrict__ bsum, int G) {
    __shared__ int ws[4];
    int tid = threadIdx.x;
    int base = blockIdx.x * 1024 + tid * 4;
    int a0 = 0, a1 = 0, a2 = 0, a3 = 0;
    if (base + 0 < G) a0 = cum[base + 0];
    if (base + 1 < G) a1 = cum[base + 1];
    if (base + 2 < G) a2 = cum[base + 2];
    if (base + 3 < G) a3 = cum[base + 3];
    int s = a0 + a1 + a2 + a3;
    int lane = tid & 63;
    int v = s;
#pragma unroll
    for (int off = 1; off < 64; off <<= 1) {
        int u = __shfl_up(v, off, 64);
        if (lane >= off) v += u;
    }
    if (lane == 63) ws[tid >> 6] = v;
    __syncthreads();
    int wof = 0;
    for (int w = 0; w < (tid >> 6); ++w) wof += ws[w];
    int excl = wof + v - s;
    int r0 = excl + a0, r1 = r0 + a1, r2 = r1 + a2, r3 = r2 + a3;
    if (base + 0 < G) cum[base + 0] = r0;
    if (base + 1 < G) cum[base + 1] = r1;
    if (base + 2 < G) cum[base + 2] = r2;
    if (base + 3 < G) cum[base + 3] = r3;
    if (tid == 255) bsum[blockIdx.x] = excl + s;
}

__global__ void k_scan2(int* __restrict__ bsum, int nb) {
    int t = threadIdx.x;  // 64 threads, nb <= 64
    int v = (t < nb) ? bsum[t] : 0;
#pragma unroll
    for (int off = 1; off < 64; off <<= 1) {
        int u = __shfl_up(v, off, 64);
        if (t >= off) v += u;
    }
    if (t < nb) bsum[t] = v;
}

__global__ void k_gid(const int* __restrict__ ids, const int* __restrict__ cum,
                      const int* __restrict__ bsum, int* __restrict__ gid,
                      int* __restrict__ gstart, int* __restrict__ ngr, int n) {
    int i = blockIdx.x * blockDim.x + threadIdx.x;
    if (i >= n) return;
    int v = ids[i];
    int blk = v >> 10;
    int g = cum[v] + (blk ? bsum[blk - 1] : 0) - 1;
    gid[i] = g;
    if (i == 0 || ids[i - 1] != v) gstart[g] = i;
    if (i == n - 1) { gstart[g + 1] = n; *ngr = g + 1; }
}

// E1 = emb @ W1b^T + b1. 128-row block, LDS-staged, one barrier.
__global__ __launch_bounds__(256, 2) void k_egemm(
    const float* __restrict__ emb, const unsigned short* __restrict__ Wf,
    const float* __restrict__ b1, float* __restrict__ E1, int G) {
    __shared__ __align__(16) float ebuf[16384];   // 64KB: 128 rows f32
    int tid = threadIdx.x, lane = tid & 63, wid = tid >> 6;
    int p = lane & 15, q = lane >> 4;
    int wr = wid >> 1, wc = wid & 1;
    int row0 = blockIdx.x * 128;

    short8 bfr[4][4];
#pragma unroll
    for (int t = 0; t < 4; ++t)
#pragma unroll
        for (int kk = 0; kk < 4; ++kk)
            bfr[t][kk] = *(const short8*)&Wf[(size_t)((wc * 4 + t) * 4 + kk) * 512 + lane * 8];
    float b1v[4];
#pragma unroll
    for (int t = 0; t < 4; ++t) b1v[t] = b1[wc * 64 + t * 16 + p];

    long long maxb = (long long)G * 512 - 16;
#pragma unroll
    for (int k = 0; k < 16; ++k) {
        int doff = k * 4096 + tid * 16;
        int r = doff >> 9;
        long long s = (long long)(row0 + r) * 512 + (long long)((doff & 511) ^ ((r & 7) << 4));
        s = s < maxb ? s : maxb;
        dma16((const char*)emb + s, (char*)ebuf + doff);
    }
    asm volatile("s_waitcnt vmcnt(0)" ::: "memory");
    __builtin_amdgcn_s_barrier();
    __builtin_amdgcn_sched_barrier(0);

    int sw = (p & 7) << 4;
#pragma unroll
    for (int tt = 0; tt < 4; ++tt) {
        int lr = wr * 64 + tt * 16 + p;
        short8 afr[4];
#pragma unroll
        for (int kk = 0; kk < 4; ++kk) {
            int boff = lr * 512 + kk * 128 + q * 32;
            float4 v0 = lds_rd16(ebuf, boff, sw);
            float4 v1 = lds_rd16(ebuf, boff + 16, sw);
            afr[kk] = pack8(v0, v1);
        }
        f32x4 acc[4];
#pragma unroll
        for (int t = 0; t < 4; ++t) acc[t] = f32x4{0.f, 0.f, 0.f, 0.f};
#pragma unroll
        for (int t = 0; t < 4; ++t)
#pragma unroll
            for (int kk = 0; kk < 4; ++kk)
                acc[t] = __builtin_amdgcn_mfma_f32_16x16x32_bf16(afr[kk], bfr[t][kk], acc[t], 0, 0, 0);
#pragma unroll
        for (int t = 0; t < 4; ++t) {
            int colb = wc * 64 + t * 16 + p;
#pragma unroll
            for (int rg = 0; rg < 4; ++rg) {
                int rr = row0 + wr * 64 + tt * 16 + q * 4 + rg;
                if (rr < G) E1[(size_t)rr * 128 + colb] = acc[t][rg] + b1v[t];
            }
        }
    }
}

// x_out = x @ W1a^T + E1[gid]  +  FUSED group sums from the LDS-staged x.
// Group walk per thread (col c, 64-row half h): fully-contained groups ->
// direct bf16 mean into imps (unique writer); crossing groups -> one
// atomicAdd partial into zeroed segsum (finished by k_fix).
__global__ __launch_bounds__(256, 2) void k_xgemm(
    const float* __restrict__ x, const unsigned short* __restrict__ Wf,
    const int* __restrict__ gid, const float* __restrict__ E1,
    const int* __restrict__ gstart, const int* __restrict__ ngr,
    float* __restrict__ out, unsigned short* __restrict__ imps,
    float* __restrict__ segsum, int N, int nwg) {
    __shared__ __align__(16) float xbuf[16384];   // 64KB: 128 rows f32
    int tid = threadIdx.x, lane = tid & 63, wid = tid >> 6;
    int p = lane & 15, q = lane >> 4;
    int wr = wid >> 1, wc = wid & 1;
    // bijective XCD swizzle (m204)
    int orig = blockIdx.x;
    int qq = nwg >> 3, rr8 = nwg & 7;
    int xcd = orig & 7, idx = orig >> 3;
    int bid = (xcd < rr8 ? xcd * (qq + 1) : rr8 * (qq + 1) + (xcd - rr8) * qq) + idx;
    int row0 = bid * 128;

    short8 bfr[4][4];
#pragma unroll
    for (int t = 0; t < 4; ++t)
#pragma unroll
        for (int kk = 0; kk < 4; ++kk)
            bfr[t][kk] = *(const short8*)&Wf[(size_t)((wc * 4 + t) * 4 + kk) * 512 + lane * 8];

    int gt0 = gid[min(row0 + wr * 64 + 0 * 16 + p, N - 1)];
    int gt1 = gid[min(row0 + wr * 64 + 1 * 16 + p, N - 1)];
    int gt2 = gid[min(row0 + wr * 64 + 2 * 16 + p, N - 1)];
    int gt3 = gid[min(row0 + wr * 64 + 3 * 16 + p, N - 1)];

    long long maxb = (long long)N * 512 - 16;
#pragma unroll
    for (int k = 0; k < 16; ++k) {
        int doff = k * 4096 + tid * 16;
        int r = doff >> 9;
        long long s = (long long)(row0 + r) * 512 + (long long)((doff & 511) ^ ((r & 7) << 4));
        s = s < maxb ? s : maxb;
        dma16((const char*)x + s, (char*)xbuf + doff);
    }
    asm volatile("s_waitcnt vmcnt(0)" ::: "memory");
    __builtin_amdgcn_s_barrier();
    __builtin_amdgcn_sched_barrier(0);

    int sw = (p & 7) << 4;
#pragma unroll
    for (int tt = 0; tt < 4; ++tt) {
        int gt = (tt == 0) ? gt0 : (tt == 1) ? gt1 : (tt == 2) ? gt2 : gt3;
        int lr = wr * 64 + tt * 16 + p;
        short8 afr[4];
#pragma unroll
        for (int kk = 0; kk < 4; ++kk) {
            int boff = lr * 512 + kk * 128 + q * 32;
            float4 v0 = lds_rd16(xbuf, boff, sw);
            float4 v1 = lds_rd16(xbuf, boff + 16, sw);
            afr[kk] = pack8(v0, v1);
        }
        int g4[4];
#pragma unroll
        for (int rg = 0; rg < 4; ++rg) g4[rg] = __shfl(gt, q * 4 + rg);
        float ev[4][4];
#pragma unroll
        for (int t = 0; t < 4; ++t) {
            int colb = wc * 64 + t * 16 + p;
#pragma unroll
            for (int rg = 0; rg < 4; ++rg)
                ev[t][rg] = E1[(size_t)g4[rg] * 128 + colb];
        }
        f32x4 acc[4];
#pragma unroll
        for (int t = 0; t < 4; ++t) acc[t] = f32x4{0.f, 0.f, 0.f, 0.f};
#pragma unroll
        for (int t = 0; t < 4; ++t)
#pragma unroll
            for (int kk = 0; kk < 4; ++kk)
                acc[t] = __builtin_amdgcn_mfma_f32_16x16x32_bf16(afr[kk], bfr[t][kk], acc[t], 0, 0, 0);
#pragma unroll
        for (int t = 0; t < 4; ++t) {
            int colb = wc * 64 + t * 16 + p;
#pragma unroll
            for (int rg = 0; rg < 4; ++rg) {
                int rr = row0 + wr * 64 + tt * 16 + q * 4 + rg;
                if (rr < N) out[(size_t)rr * 128 + colb] = acc[t][rg] + ev[t][rg];
            }
        }
    }

    // ---- fused group sums from LDS (x already staged; out-stores in flight) ----
    int c = tid & 127;
    int h = tid >> 7;
    int lo = row0 + h * 64;
    if (lo < N) {
        int hi = min(lo + 64, N);
        int ng = *ngr;
        int g = gid[lo];
        int rs = gstart[g];
        for (;;) {
            int re = gstart[g + 1];
            int a = rs > lo ? rs : lo;
            int b = re < hi ? re : hi;
            float s = 0.f;
            for (int r = a; r < b; ++r) {
                int lrr = r - row0;
                s += *(const float*)((const char*)xbuf + lrr * 512 + ((c * 4) ^ ((lrr & 7) << 4)));
            }
            bool contained = (rs >= lo) && (re <= hi);
            if (contained) {
                if (g < ng - 1)
                    imps[(size_t)g * 128 + c] = f2bf(s / (float)(re - rs));
            } else {
                atomicAdd(&segsum[(size_t)g * 128 + c], s);
            }
            if (re >= hi) break;
            rs = re; ++g;
        }
    }
}

// Finish crossing groups (segsum/n) and emb-copy for unwritten tail groups.
__global__ __launch_bounds__(256) void k_fix(
    const float* __restrict__ segsum, const float* __restrict__ emb,
    const int* __restrict__ gstart, const int* __restrict__ ngr,
    unsigned short* __restrict__ imps, int G) {
    int g = blockIdx.x * 4 + (threadIdx.x >> 6);
    int lane = threadIdx.x & 63;
    if (g >= G) return;
    int ng = *ngr;
    float2 m;
    if (g < ng - 1) {
        int a = gstart[g], b = gstart[g + 1];
        if ((a >> 6) == ((b - 1) >> 6)) return;  // contained: imps already written
        float inv = 1.0f / (float)(b - a);
        float2 s = *(const float2*)&segsum[(size_t)g * 128 + lane * 2];
        m.x = s.x * inv; m.y = s.y * inv;
    } else {
        m = *(const float2*)&emb[(size_t)g * 128 + lane * 2];
    }
    unsigned int pk = (unsigned int)f2bf(m.x) | ((unsigned int)f2bf(m.y) << 16);
    ((unsigned int*)imps)[(size_t)g * 64 + lane] = pk;
}

// imputed_out = emb @ W2a^T + imps @ W2b^T + b2. 64-row block, LDS-staged.
__global__ __launch_bounds__(256, 2) void k_igemm(
    const float* __restrict__ emb, const unsigned short* __restrict__ imps,
    const unsigned short* __restrict__ Waf, const unsigned short* __restrict__ Wbf,
    const float* __restrict__ b2, float* __restrict__ out2, int G) {
    __shared__ __align__(16) float ebuf[8192];            // 32KB: 64 rows f32
    __shared__ __align__(16) unsigned short ibuf[8192];   // 16KB: 64 rows bf16
    int tid = threadIdx.x, lane = tid & 63, wid = tid >> 6;
    int p = lane & 15, q = lane >> 4;
    int wr = wid >> 1, wc = wid & 1;
    int row0 = blockIdx.x * 64;

    short8 bfrA[4][4], bfrB[4][4];
#pragma unroll
    for (int t = 0; t < 4; ++t)
#pragma unroll
        for (int kk = 0; kk < 4; ++kk) {
            bfrA[t][kk] = *(const short8*)&Waf[(size_t)((wc * 4 + t) * 4 + kk) * 512 + lane * 8];
            bfrB[t][kk] = *(const short8*)&Wbf[(size_t)((wc * 4 + t) * 4 + kk) * 512 + lane * 8];
        }
    float b2v[4];
#pragma unroll
    for (int t = 0; t < 4; ++t) b2v[t] = b2[wc * 64 + t * 16 + p];

    long long maxe = (long long)G * 512 - 16;
    long long maxi = (long long)G * 256 - 16;
#pragma unroll
    for (int k = 0; k < 8; ++k) {
        int doff = k * 4096 + tid * 16;
        int r = doff >> 9;
        long long s = (long long)(row0 + r) * 512 + (long long)((doff & 511) ^ ((r & 7) << 4));
        s = s < maxe ? s : maxe;
        dma16((const char*)emb + s, (char*)ebuf + doff);
    }
#pragma unroll
    for (int k = 0; k < 4; ++k) {
        int doff = k * 4096 + tid * 16;
        int r = doff >> 8;
        long long s = (long long)(row0 + r) * 256 + (long long)((doff & 255) ^ ((r & 7) << 4));
        s = s < maxi ? s : maxi;
        dma16((const char*)imps + s, (char*)ibuf + doff);
    }
    asm volatile("s_waitcnt vmcnt(0)" ::: "memory");
    __builtin_amdgcn_s_barrier();
    __builtin_amdgcn_sched_barrier(0);

    int sw = (p & 7) << 4;
#pragma unroll
    for (int tt = 0; tt < 2; ++tt) {
        int lr = wr * 32 + tt * 16 + p;
        short8 ae[4], ia[4];
#pragma unroll
        for (int kk = 0; kk < 4; ++kk) {
            int boff = lr * 512 + kk * 128 + q * 32;
            float4 v0 = lds_rd16(ebuf, boff, sw);
            float4 v1 = lds_rd16(ebuf, boff + 16, sw);
            ae[kk] = pack8(v0, v1);
            int boff2 = lr * 256 + ((kk * 64 + q * 16) ^ sw);
            ia[kk] = *(const short8*)((const char*)ibuf + boff2);
        }
        f32x4 acc[4];
#pragma unroll
        for (int t = 0; t < 4; ++t) acc[t] = f32x4{0.f, 0.f, 0.f, 0.f};
#pragma unroll
        for (int kk = 0; kk < 4; ++kk)
#pragma unroll
            for (int t = 0; t < 4; ++t) {
                acc[t] = __builtin_amdgcn_mfma_f32_16x16x32_bf16(ae[kk], bfrA[t][kk], acc[t], 0, 0, 0);
                acc[t] = __builtin_amdgcn_mfma_f32_16x16x32_bf16(ia[kk], bfrB[t][kk], acc[t], 0, 0, 0);
            }
#pragma unroll
        for (int t = 0; t < 4; ++t) {
            int colb = wc * 64 + t * 16 + p;
#pragma unroll
            for (int rg = 0; rg < 4; ++rg) {
                int rr = row0 + wr * 32 + tt * 16 + q * 4 + rg;
                if (rr < G) out2[(size_t)rr * 128 + colb] = acc[t][rg] + b2v[t];
            }
        }
    }
}

extern "C" void kernel_launch(void* const* d_in, const int* in_sizes, int n_in,
                              void* d_out, int out_size, void* d_ws, size_t ws_size,
                              hipStream_t stream) {
    const float* x   = (const float*)d_in[0];
    const float* emb = (const float*)d_in[1];
    const float* W1  = (const float*)d_in[2];
    const float* b1  = (const float*)d_in[3];
    const float* W2  = (const float*)d_in[4];
    const float* b2  = (const float*)d_in[5];
    const int*   ids = (const int*)d_in[6];
    const int H = 128;
    const int N = in_sizes[6];
    const int G = in_sizes[1] / H;

    float* out  = (float*)d_out;
    float* out2 = out + (size_t)N * H;
    float* E1   = out2;  // E1 scratch lives in imputed_out region (overwritten by k_igemm last)

    char* ws = (char*)d_ws;
    size_t off = 0;
    float* segsum = (float*)(ws + off); off += (size_t)G * H * 4;
    int*   cum    = (int*)(ws + off);   off += (size_t)G * 4;
    size_t zbytes = off;                              // zero region: segsum + cum
    off = (off + 255) & ~(size_t)255;
    int* bsum   = (int*)(ws + off); off += 64 * 4;          off = (off + 255) & ~(size_t)255;
    int* gid    = (int*)(ws + off); off += (size_t)N * 4;   off = (off + 255) & ~(size_t)255;
    int* gstart = (int*)(ws + off); off += (size_t)(G + 1) * 4; off = (off + 255) & ~(size_t)255;
    int* ngr    = (int*)(ws + off); off += 256;
    unsigned short* W1af = (unsigned short*)(ws + off); off += (size_t)H * H * 2;
    unsigned short* W1bf = (unsigned short*)(ws + off); off += (size_t)H * H * 2;
    unsigned short* W2af = (unsigned short*)(ws + off); off += (size_t)H * H * 2;
    unsigned short* W2bf = (unsigned short*)(ws + off); off += (size_t)H * H * 2;
    unsigned short* imps = (unsigned short*)(ws + off); off += (size_t)G * H * 2;

    int n16 = (int)((zbytes + 15) / 16);
    int nb = (G + 1023) >> 10;
    int nwgX = (N + 127) >> 7;
    int nwgE = (G + 127) >> 7;
    int nwgI = (G + 63) >> 6;
    k_zero<<<(n16 + 255) / 256, 256, 0, stream>>>((uint4*)ws, n16);
    k_convw<<<32, 256, 0, stream>>>(W1, W2, W1af, W1bf, W2af, W2bf);
    k_mark<<<(N + 255) / 256, 256, 0, stream>>>(ids, cum, N);
    k_scan1<<<nb, 256, 0, stream>>>(cum, bsum, G);
    k_scan2<<<1, 64, 0, stream>>>(bsum, nb);
    k_gid<<<(N + 255) / 256, 256, 0, stream>>>(ids, cum, bsum, gid, gstart, ngr, N);
    k_egemm<<<nwgE, 256, 0, stream>>>(emb, W1bf, b1, E1, G);
    k_xgemm<<<nwgX, 256, 0, stream>>>(x, W1af, gid, E1, gstart, ngr, out, imps, segsum, N, nwgX);
    k_fix<<<(G + 3) / 4, 256, 0, stream>>>(segsum, emb, gstart, ngr, imps, G);
    k_igemm<<<nwgI, 256, 0, stream>>>(emb, imps, W2af, W2bf, b2, out2, G);
}

// Round 10
// 208.210 us; speedup vs baseline: 3.5572x; 1.0523x over previous
//
#include <hip/hip_runtime.h>

typedef __attribute__((ext_vector_type(8))) short short8;
typedef __attribute__((ext_vector_type(4))) float f32x4;

static __device__ __forceinline__ unsigned short f2bf(float f) {
    union { float f; unsigned int u; } v; v.f = f;
    unsigned int r = v.u + 0x7fffu + ((v.u >> 16) & 1u);  // RNE
    return (unsigned short)(r >> 16);
}

static __device__ __forceinline__ short8 pack8(float4 a, float4 b) {
    short8 r;
    r[0] = (short)f2bf(a.x); r[1] = (short)f2bf(a.y);
    r[2] = (short)f2bf(a.z); r[3] = (short)f2bf(a.w);
    r[4] = (short)f2bf(b.x); r[5] = (short)f2bf(b.y);
    r[6] = (short)f2bf(b.z); r[7] = (short)f2bf(b.w);
    return r;
}

static __device__ __forceinline__ void dma16(const void* g, void* l) {
    __builtin_amdgcn_global_load_lds(
        (const __attribute__((address_space(1))) unsigned int*)g,
        (__attribute__((address_space(3))) unsigned int*)l, 16, 0, 0);
}

static __device__ __forceinline__ float4 lds_rd16(const float* buf, int boff, int sw) {
    return *(const float4*)((const char*)buf + (boff ^ sw));
}

__global__ void k_zero(uint4* p, int n16) {
    int i = blockIdx.x * blockDim.x + threadIdx.x;
    if (i < n16) p[i] = uint4{0u, 0u, 0u, 0u};
}

// Pack W1,W2 (f32 [128][256]) into 4 fragment-ordered bf16 arrays:
// frag f=(wc*4+t)*4+kk, element [f*512 + lane*8 + j] -> contiguous 1KB bfr loads.
__global__ void k_convw(const float* __restrict__ W1, const float* __restrict__ W2,
                        unsigned short* W1af, unsigned short* W1bf,
                        unsigned short* W2af, unsigned short* W2bf) {
    int T = blockIdx.x * 256 + threadIdx.x;   // 8192 total
    int mat = T >> 11;
    int rem = T & 2047;
    int f = rem >> 6, lane = rem & 63;
    int wc = f >> 4, t = (f >> 2) & 3, kk = f & 3;
    int p = lane & 15, q = lane >> 4;
    int row = wc * 64 + t * 16 + p;
    int col = (mat & 1) * 128 + kk * 32 + q * 8;
    const float* src = (mat < 2 ? W1 : W2) + row * 256 + col;
    unsigned short* dst = (mat == 0 ? W1af : mat == 1 ? W1bf : mat == 2 ? W2af : W2bf);
    short8 v;
#pragma unroll
    for (int j = 0; j < 8; ++j) v[j] = (short)f2bf(src[j]);
    *(short8*)&dst[(size_t)f * 512 + lane * 8] = v;
}

__global__ void k_mark(const int* __restrict__ ids, int* __restrict__ cum, int n) {
    int i = blockIdx.x * blockDim.x + threadIdx.x;
    if (i < n) cum[ids[i]] = 1;
}

// 2-level scan: per-block inclusive scan of 1024 ints + block sums
__global__ __launch_bounds__(256) void k_scan1(int* __restrict__ cum, int* __restrict__ bsum, int G) {
    __shared__ int ws[4];
    int tid = threadIdx.x;
    int base = blockIdx.x * 1024 + tid * 4;
    int a0 = 0, a1 = 0, a2 = 0, a3 = 0;
    if (base + 0 < G) a0 = cum[base + 0];
    if (base + 1 < G) a1 = cum[base + 1];
    if (base + 2 < G) a2 = cum[base + 2];
    if (base + 3 < G) a3 = cum[base + 3];
    int s = a0 + a1 + a2 + a3;
    int lane = tid & 63;
    int v = s;
#pragma unroll
    for (int off = 1; off < 64; off <<= 1) {
        int u = __shfl_up(v, off, 64);
        if (lane >= off) v += u;
    }
    if (lane == 63) ws[tid >> 6] = v;
    __syncthreads();
    int wof = 0;
    for (int w = 0; w < (tid >> 6); ++w) wof += ws[w];
    int excl = wof + v - s;
    int r0 = excl + a0, r1 = r0 + a1, r2 = r1 + a2, r3 = r2 + a3;
    if (base + 0 < G) cum[base + 0] = r0;
    if (base + 1 < G) cum[base + 1] = r1;
    if (base + 2 < G) cum[base + 2] = r2;
    if (base + 3 < G) cum[base + 3] = r3;
    if (tid == 255) bsum[blockIdx.x] = excl + s;
}

__global__ void k_scan2(int* __restrict__ bsum, int nb) {
    int t = threadIdx.x;  // 64 threads, nb <= 64
    int v = (t < nb) ? bsum[t] : 0;
#pragma unroll
    for (int off = 1; off < 64; off <<= 1) {
        int u = __shfl_up(v, off, 64);
        if (t >= off) v += u;
    }
    if (t < nb) bsum[t] = v;
}

__global__ void k_gid(const int* __restrict__ ids, const int* __restrict__ cum,
                      const int* __restrict__ bsum, int* __restrict__ gid,
                      int* __restrict__ gstart, int* __restrict__ ngr, int n) {
    int i = blockIdx.x * blockDim.x + threadIdx.x;
    if (i >= n) return;
    int v = ids[i];
    int blk = v >> 10;
    int g = cum[v] + (blk ? bsum[blk - 1] : 0) - 1;
    gid[i] = g;
    if (i == 0 || ids[i - 1] != v) gstart[g] = i;
    if (i == n - 1) { gstart[g + 1] = n; *ngr = g + 1; }
}

// E1 = emb @ W1b^T + b1. 128-row block, LDS-staged, one barrier.
__global__ __launch_bounds__(256, 2) void k_egemm(
    const float* __restrict__ emb, const unsigned short* __restrict__ Wf,
    const float* __restrict__ b1, float* __restrict__ E1, int G) {
    __shared__ __align__(16) float ebuf[16384];   // 64KB: 128 rows f32
    int tid = threadIdx.x, lane = tid & 63, wid = tid >> 6;
    int p = lane & 15, q = lane >> 4;
    int wr = wid >> 1, wc = wid & 1;
    int row0 = blockIdx.x * 128;

    short8 bfr[4][4];
#pragma unroll
    for (int t = 0; t < 4; ++t)
#pragma unroll
        for (int kk = 0; kk < 4; ++kk)
            bfr[t][kk] = *(const short8*)&Wf[(size_t)((wc * 4 + t) * 4 + kk) * 512 + lane * 8];
    float b1v[4];
#pragma unroll
    for (int t = 0; t < 4; ++t) b1v[t] = b1[wc * 64 + t * 16 + p];

    long long maxb = (long long)G * 512 - 16;
#pragma unroll
    for (int k = 0; k < 16; ++k) {
        int doff = k * 4096 + tid * 16;
        int r = doff >> 9;
        long long s = (long long)(row0 + r) * 512 + (long long)((doff & 511) ^ ((r & 7) << 4));
        s = s < maxb ? s : maxb;
        dma16((const char*)emb + s, (char*)ebuf + doff);
    }
    asm volatile("s_waitcnt vmcnt(0)" ::: "memory");
    __builtin_amdgcn_s_barrier();
    __builtin_amdgcn_sched_barrier(0);

    int sw = (p & 7) << 4;
#pragma unroll
    for (int tt = 0; tt < 4; ++tt) {
        int lr = wr * 64 + tt * 16 + p;
        short8 afr[4];
#pragma unroll
        for (int kk = 0; kk < 4; ++kk) {
            int boff = lr * 512 + kk * 128 + q * 32;
            float4 v0 = lds_rd16(ebuf, boff, sw);
            float4 v1 = lds_rd16(ebuf, boff + 16, sw);
            afr[kk] = pack8(v0, v1);
        }
        f32x4 acc[4];
#pragma unroll
        for (int t = 0; t < 4; ++t) acc[t] = f32x4{0.f, 0.f, 0.f, 0.f};
#pragma unroll
        for (int t = 0; t < 4; ++t)
#pragma unroll
            for (int kk = 0; kk < 4; ++kk)
                acc[t] = __builtin_amdgcn_mfma_f32_16x16x32_bf16(afr[kk], bfr[t][kk], acc[t], 0, 0, 0);
#pragma unroll
        for (int t = 0; t < 4; ++t) {
            int colb = wc * 64 + t * 16 + p;
#pragma unroll
            for (int rg = 0; rg < 4; ++rg) {
                int rr = row0 + wr * 64 + tt * 16 + q * 4 + rg;
                if (rr < G) E1[(size_t)rr * 128 + colb] = acc[t][rg] + b1v[t];
            }
        }
    }
}

// x_out = x @ W1a^T + E1[gid]  +  fused group means.
// Scan uses LDS-staged gids (no gstart walk); only 2 edge gid loads per half.
// Contained groups (same 64-aligned window) -> direct imps write (unique
// writer); crossing groups -> atomicAdd partial into zeroed segsum (k_fix).
__global__ __launch_bounds__(256, 2) void k_xgemm(
    const float* __restrict__ x, const unsigned short* __restrict__ Wf,
    const int* __restrict__ gid, const float* __restrict__ E1,
    const int* __restrict__ ngr,
    float* __restrict__ out, unsigned short* __restrict__ imps,
    float* __restrict__ segsum, int N, int nwg) {
    __shared__ __align__(16) float xbuf[16384];   // 64KB: 128 rows f32
    __shared__ int gids[128];
    int tid = threadIdx.x, lane = tid & 63, wid = tid >> 6;
    int p = lane & 15, q = lane >> 4;
    int wr = wid >> 1, wc = wid & 1;
    // bijective XCD swizzle (m204)
    int orig = blockIdx.x;
    int qq = nwg >> 3, rr8 = nwg & 7;
    int xcd = orig & 7, idx = orig >> 3;
    int bid = (xcd < rr8 ? xcd * (qq + 1) : rr8 * (qq + 1) + (xcd - rr8) * qq) + idx;
    int row0 = bid * 128;

    short8 bfr[4][4];
#pragma unroll
    for (int t = 0; t < 4; ++t)
#pragma unroll
        for (int kk = 0; kk < 4; ++kk)
            bfr[t][kk] = *(const short8*)&Wf[(size_t)((wc * 4 + t) * 4 + kk) * 512 + lane * 8];

    int gt[4];
#pragma unroll
    for (int tt = 0; tt < 4; ++tt)
        gt[tt] = gid[min(row0 + wr * 64 + tt * 16 + p, N - 1)];

    // scan geometry + edge loads (issued early, hidden under DMA)
    int c = tid & 127, h = tid >> 7;
    int lo = row0 + h * 64;
    int hi = min(lo + 64, N);
    int gbefore = -1, gafter = -1;
    if (lo > 0 && lo < N) gbefore = gid[lo - 1];
    if (hi < N) gafter = gid[hi];

    long long maxb = (long long)N * 512 - 16;
#pragma unroll
    for (int k = 0; k < 16; ++k) {
        int doff = k * 4096 + tid * 16;
        int r = doff >> 9;
        long long s = (long long)(row0 + r) * 512 + (long long)((doff & 511) ^ ((r & 7) << 4));
        s = s < maxb ? s : maxb;
        dma16((const char*)x + s, (char*)xbuf + doff);
    }
    if (wc == 0) {   // stage this block's gids into LDS (rows wr*64 .. wr*64+63)
#pragma unroll
        for (int tt = 0; tt < 4; ++tt)
            gids[wr * 64 + tt * 16 + p] = gt[tt];
    }
    asm volatile("s_waitcnt vmcnt(0) lgkmcnt(0)" ::: "memory");
    __builtin_amdgcn_s_barrier();
    __builtin_amdgcn_sched_barrier(0);

    // hoisted E1 gather: 64 independent loads -> deep MLP
    float ev[4][4][4];
#pragma unroll
    for (int tt = 0; tt < 4; ++tt) {
        int g4[4];
#pragma unroll
        for (int rg = 0; rg < 4; ++rg) g4[rg] = __shfl(gt[tt], q * 4 + rg);
#pragma unroll
        for (int t = 0; t < 4; ++t) {
            int colb = wc * 64 + t * 16 + p;
#pragma unroll
            for (int rg = 0; rg < 4; ++rg)
                ev[tt][t][rg] = E1[(size_t)g4[rg] * 128 + colb];
        }
    }

    int sw = (p & 7) << 4;
#pragma unroll
    for (int tt = 0; tt < 4; ++tt) {
        int lr = wr * 64 + tt * 16 + p;
        short8 afr[4];
#pragma unroll
        for (int kk = 0; kk < 4; ++kk) {
            int boff = lr * 512 + kk * 128 + q * 32;
            float4 v0 = lds_rd16(xbuf, boff, sw);
            float4 v1 = lds_rd16(xbuf, boff + 16, sw);
            afr[kk] = pack8(v0, v1);
        }
        f32x4 acc[4];
#pragma unroll
        for (int t = 0; t < 4; ++t) acc[t] = f32x4{0.f, 0.f, 0.f, 0.f};
#pragma unroll
        for (int t = 0; t < 4; ++t)
#pragma unroll
            for (int kk = 0; kk < 4; ++kk)
                acc[t] = __builtin_amdgcn_mfma_f32_16x16x32_bf16(afr[kk], bfr[t][kk], acc[t], 0, 0, 0);
#pragma unroll
        for (int t = 0; t < 4; ++t) {
            int colb = wc * 64 + t * 16 + p;
#pragma unroll
            for (int rg = 0; rg < 4; ++rg) {
                int rr = row0 + wr * 64 + tt * 16 + q * 4 + rg;
                if (rr < N) out[(size_t)rr * 128 + colb] = acc[t][rg] + ev[tt][t][rg];
            }
        }
    }

    // ---- fused group means from LDS (batched reads, no gstart walk) ----
    if (lo < N) {
        int nwin = hi - lo;                 // 1..64
        int gbase = h * 64;
        int ng = *ngr;
        int gcur = gids[gbase];
        bool open_left = (gcur == gbefore);
        int rs = lo;
        float s = 0.f;
        for (int bb = 0; bb < nwin; bb += 8) {
            float v[8];
            int gn[8];
#pragma unroll
            for (int j = 0; j < 8; ++j) {
                int rr = bb + j; rr = rr < nwin - 1 ? rr : nwin - 1;
                int lrr = gbase + rr;
                v[j] = *(const float*)((const char*)xbuf + lrr * 512 + ((c * 4) ^ ((lrr & 7) << 4)));
                int rn = bb + j + 1; rn = rn < nwin - 1 ? rn : nwin - 1;
                gn[j] = gids[gbase + rn];
            }
#pragma unroll
            for (int j = 0; j < 8; ++j) {
                int r = bb + j;
                if (r < nwin) {
                    s += v[j];
                    bool at_end = (r + 1 >= nwin);
                    int gnext = at_end ? gafter : gn[j];
                    if (at_end || gnext != gcur) {
                        bool open_right = at_end && (gafter == gcur);
                        if (!open_left && !open_right) {
                            if (gcur < ng - 1)
                                imps[(size_t)gcur * 128 + c] = f2bf(s / (float)(lo + r + 1 - rs));
                        } else {
                            atomicAdd(&segsum[(size_t)gcur * 128 + c], s);
                        }
                        s = 0.f; rs = lo + r + 1; gcur = gnext; open_left = false;
                    }
                }
            }
        }
    }
}

// Finish crossing groups (segsum/n) and emb-copy for unwritten tail groups.
__global__ __launch_bounds__(256) void k_fix(
    const float* __restrict__ segsum, const float* __restrict__ emb,
    const int* __restrict__ gstart, const int* __restrict__ ngr,
    unsigned short* __restrict__ imps, int G) {
    int g = blockIdx.x * 4 + (threadIdx.x >> 6);
    int lane = threadIdx.x & 63;
    if (g >= G) return;
    int ng = *ngr;
    float2 m;
    if (g < ng - 1) {
        int a = gstart[g], b = gstart[g + 1];
        if ((a >> 6) == ((b - 1) >> 6)) return;  // contained: imps already written
        float inv = 1.0f / (float)(b - a);
        float2 s = *(const float2*)&segsum[(size_t)g * 128 + lane * 2];
        m.x = s.x * inv; m.y = s.y * inv;
    } else {
        m = *(const float2*)&emb[(size_t)g * 128 + lane * 2];
    }
    unsigned int pk = (unsigned int)f2bf(m.x) | ((unsigned int)f2bf(m.y) << 16);
    ((unsigned int*)imps)[(size_t)g * 64 + lane] = pk;
}

// imputed_out = emb @ W2a^T + imps @ W2b^T + b2. 64-row block, LDS-staged.
__global__ __launch_bounds__(256, 2) void k_igemm(
    const float* __restrict__ emb, const unsigned short* __restrict__ imps,
    const unsigned short* __restrict__ Waf, const unsigned short* __restrict__ Wbf,
    const float* __restrict__ b2, float* __restrict__ out2, int G) {
    __shared__ __align__(16) float ebuf[8192];            // 32KB: 64 rows f32
    __shared__ __align__(16) unsigned short ibuf[8192];   // 16KB: 64 rows bf16
    int tid = threadIdx.x, lane = tid & 63, wid = tid >> 6;
    int p = lane & 15, q = lane >> 4;
    int wr = wid >> 1, wc = wid & 1;
    int row0 = blockIdx.x * 64;

    short8 bfrA[4][4], bfrB[4][4];
#pragma unroll
    for (int t = 0; t < 4; ++t)
#pragma unroll
        for (int kk = 0; kk < 4; ++kk) {
            bfrA[t][kk] = *(const short8*)&Waf[(size_t)((wc * 4 + t) * 4 + kk) * 512 + lane * 8];
            bfrB[t][kk] = *(const short8*)&Wbf[(size_t)((wc * 4 + t) * 4 + kk) * 512 + lane * 8];
        }
    float b2v[4];
#pragma unroll
    for (int t = 0; t < 4; ++t) b2v[t] = b2[wc * 64 + t * 16 + p];

    long long maxe = (long long)G * 512 - 16;
    long long maxi = (long long)G * 256 - 16;
#pragma unroll
    for (int k = 0; k < 8; ++k) {
        int doff = k * 4096 + tid * 16;
        int r = doff >> 9;
        long long s = (long long)(row0 + r) * 512 + (long long)((doff & 511) ^ ((r & 7) << 4));
        s = s < maxe ? s : maxe;
        dma16((const char*)emb + s, (char*)ebuf + doff);
    }
#pragma unroll
    for (int k = 0; k < 4; ++k) {
        int doff = k * 4096 + tid * 16;
        int r = doff >> 8;
        long long s = (long long)(row0 + r) * 256 + (long long)((doff & 255) ^ ((r & 7) << 4));
        s = s < maxi ? s : maxi;
        dma16((const char*)imps + s, (char*)ibuf + doff);
    }
    asm volatile("s_waitcnt vmcnt(0)" ::: "memory");
    __builtin_amdgcn_s_barrier();
    __builtin_amdgcn_sched_barrier(0);

    int sw = (p & 7) << 4;
#pragma unroll
    for (int tt = 0; tt < 2; ++tt) {
        int lr = wr * 32 + tt * 16 + p;
        short8 ae[4], ia[4];
#pragma unroll
        for (int kk = 0; kk < 4; ++kk) {
            int boff = lr * 512 + kk * 128 + q * 32;
            float4 v0 = lds_rd16(ebuf, boff, sw);
            float4 v1 = lds_rd16(ebuf, boff + 16, sw);
            ae[kk] = pack8(v0, v1);
            int boff2 = lr * 256 + ((kk * 64 + q * 16) ^ sw);
            ia[kk] = *(const short8*)((const char*)ibuf + boff2);
        }
        f32x4 acc[4];
#pragma unroll
        for (int t = 0; t < 4; ++t) acc[t] = f32x4{0.f, 0.f, 0.f, 0.f};
#pragma unroll
        for (int kk = 0; kk < 4; ++kk)
#pragma unroll
            for (int t = 0; t < 4; ++t) {
                acc[t] = __builtin_amdgcn_mfma_f32_16x16x32_bf16(ae[kk], bfrA[t][kk], acc[t], 0, 0, 0);
                acc[t] = __builtin_amdgcn_mfma_f32_16x16x32_bf16(ia[kk], bfrB[t][kk], acc[t], 0, 0, 0);
            }
#pragma unroll
        for (int t = 0; t < 4; ++t) {
            int colb = wc * 64 + t * 16 + p;
#pragma unroll
            for (int rg = 0; rg < 4; ++rg) {
                int rr = row0 + wr * 32 + tt * 16 + q * 4 + rg;
                if (rr < G) out2[(size_t)rr * 128 + colb] = acc[t][rg] + b2v[t];
            }
        }
    }
}

extern "C" void kernel_launch(void* const* d_in, const int* in_sizes, int n_in,
                              void* d_out, int out_size, void* d_ws, size_t ws_size,
                              hipStream_t stream) {
    const float* x   = (const float*)d_in[0];
    const float* emb = (const float*)d_in[1];
    const float* W1  = (const float*)d_in[2];
    const float* b1  = (const float*)d_in[3];
    const float* W2  = (const float*)d_in[4];
    const float* b2  = (const float*)d_in[5];
    const int*   ids = (const int*)d_in[6];
    const int H = 128;
    const int N = in_sizes[6];
    const int G = in_sizes[1] / H;

    float* out  = (float*)d_out;
    float* out2 = out + (size_t)N * H;
    float* E1   = out2;  // E1 scratch lives in imputed_out region (overwritten by k_igemm last)

    char* ws = (char*)d_ws;
    size_t off = 0;
    float* segsum = (float*)(ws + off); off += (size_t)G * H * 4;
    int*   cum    = (int*)(ws + off);   off += (size_t)G * 4;
    size_t zbytes = off;                              // zero region: segsum + cum
    off = (off + 255) & ~(size_t)255;
    int* bsum   = (int*)(ws + off); off += 64 * 4;          off = (off + 255) & ~(size_t)255;
    int* gid    = (int*)(ws + off); off += (size_t)N * 4;   off = (off + 255) & ~(size_t)255;
    int* gstart = (int*)(ws + off); off += (size_t)(G + 1) * 4; off = (off + 255) & ~(size_t)255;
    int* ngr    = (int*)(ws + off); off += 256;
    unsigned short* W1af = (unsigned short*)(ws + off); off += (size_t)H * H * 2;
    unsigned short* W1bf = (unsigned short*)(ws + off); off += (size_t)H * H * 2;
    unsigned short* W2af = (unsigned short*)(ws + off); off += (size_t)H * H * 2;
    unsigned short* W2bf = (unsigned short*)(ws + off); off += (size_t)H * H * 2;
    unsigned short* imps = (unsigned short*)(ws + off); off += (size_t)G * H * 2;

    int n16 = (int)((zbytes + 15) / 16);
    int nb = (G + 1023) >> 10;
    int nwgX = (N + 127) >> 7;
    int nwgE = (G + 127) >> 7;
    int nwgI = (G + 63) >> 6;
    k_zero<<<(n16 + 255) / 256, 256, 0, stream>>>((uint4*)ws, n16);
    k_convw<<<32, 256, 0, stream>>>(W1, W2, W1af, W1bf, W2af, W2bf);
    k_mark<<<(N + 255) / 256, 256, 0, stream>>>(ids, cum, N);
    k_scan1<<<nb, 256, 0, stream>>>(cum, bsum, G);
    k_scan2<<<1, 64, 0, stream>>>(bsum, nb);
    k_gid<<<(N + 255) / 256, 256, 0, stream>>>(ids, cum, bsum, gid, gstart, ngr, N);
    k_egemm<<<nwgE, 256, 0, stream>>>(emb, W1bf, b1, E1, G);
    k_xgemm<<<nwgX, 256, 0, stream>>>(x, W1af, gid, E1, ngr, out, imps, segsum, N, nwgX);
    k_fix<<<(G + 3) / 4, 256, 0, stream>>>(segsum, emb, gstart, ngr, imps, G);
    k_igemm<<<nwgI, 256, 0, stream>>>(emb, imps, W2af, W2bf, b2, out2, G);
}

// Round 11
// 197.583 us; speedup vs baseline: 3.7486x; 1.0538x over previous
//
#include <hip/hip_runtime.h>

typedef __attribute__((ext_vector_type(8))) short short8;
typedef __attribute__((ext_vector_type(4))) float f32x4;

static __device__ __forceinline__ unsigned short f2bf(float f) {
    union { float f; unsigned int u; } v; v.f = f;
    unsigned int r = v.u + 0x7fffu + ((v.u >> 16) & 1u);  // RNE
    return (unsigned short)(r >> 16);
}

static __device__ __forceinline__ short8 pack8(float4 a, float4 b) {
    short8 r;
    r[0] = (short)f2bf(a.x); r[1] = (short)f2bf(a.y);
    r[2] = (short)f2bf(a.z); r[3] = (short)f2bf(a.w);
    r[4] = (short)f2bf(b.x); r[5] = (short)f2bf(b.y);
    r[6] = (short)f2bf(b.z); r[7] = (short)f2bf(b.w);
    return r;
}

static __device__ __forceinline__ void dma16(const void* g, void* l) {
    __builtin_amdgcn_global_load_lds(
        (const __attribute__((address_space(1))) unsigned int*)g,
        (__attribute__((address_space(3))) unsigned int*)l, 16, 0, 0);
}

static __device__ __forceinline__ float4 lds_rd16(const float* buf, int boff, int sw) {
    return *(const float4*)((const char*)buf + (boff ^ sw));
}

__global__ void k_zero(uint4* p, int n16) {
    int i = blockIdx.x * blockDim.x + threadIdx.x;
    if (i < n16) p[i] = uint4{0u, 0u, 0u, 0u};
}

// Pack W1,W2 (f32 [128][256]) into 4 fragment-ordered bf16 arrays:
// frag f=(wc*4+t)*4+kk, element [f*512 + lane*8 + j] -> contiguous 1KB bfr loads.
__global__ void k_convw(const float* __restrict__ W1, const float* __restrict__ W2,
                        unsigned short* W1af, unsigned short* W1bf,
                        unsigned short* W2af, unsigned short* W2bf) {
    int T = blockIdx.x * 256 + threadIdx.x;   // 8192 total
    int mat = T >> 11;
    int rem = T & 2047;
    int f = rem >> 6, lane = rem & 63;
    int wc = f >> 4, t = (f >> 2) & 3, kk = f & 3;
    int p = lane & 15, q = lane >> 4;
    int row = wc * 64 + t * 16 + p;
    int col = (mat & 1) * 128 + kk * 32 + q * 8;
    const float* src = (mat < 2 ? W1 : W2) + row * 256 + col;
    unsigned short* dst = (mat == 0 ? W1af : mat == 1 ? W1bf : mat == 2 ? W2af : W2bf);
    short8 v;
#pragma unroll
    for (int j = 0; j < 8; ++j) v[j] = (short)f2bf(src[j]);
    *(short8*)&dst[(size_t)f * 512 + lane * 8] = v;
}

__global__ void k_mark(const int* __restrict__ ids, int* __restrict__ cum, int n) {
    int i = blockIdx.x * blockDim.x + threadIdx.x;
    if (i < n) cum[ids[i]] = 1;
}

// 2-level scan: per-block inclusive scan of 1024 ints + block sums
__global__ __launch_bounds__(256) void k_scan1(int* __restrict__ cum, int* __restrict__ bsum, int G) {
    __shared__ int ws[4];
    int tid = threadIdx.x;
    int base = blockIdx.x * 1024 + tid * 4;
    int a0 = 0, a1 = 0, a2 = 0, a3 = 0;
    if (base + 0 < G) a0 = cum[base + 0];
    if (base + 1 < G) a1 = cum[base + 1];
    if (base + 2 < G) a2 = cum[base + 2];
    if (base + 3 < G) a3 = cum[base + 3];
    int s = a0 + a1 + a2 + a3;
    int lane = tid & 63;
    int v = s;
#pragma unroll
    for (int off = 1; off < 64; off <<= 1) {
        int u = __shfl_up(v, off, 64);
        if (lane >= off) v += u;
    }
    if (lane == 63) ws[tid >> 6] = v;
    __syncthreads();
    int wof = 0;
    for (int w = 0; w < (tid >> 6); ++w) wof += ws[w];
    int excl = wof + v - s;
    int r0 = excl + a0, r1 = r0 + a1, r2 = r1 + a2, r3 = r2 + a3;
    if (base + 0 < G) cum[base + 0] = r0;
    if (base + 1 < G) cum[base + 1] = r1;
    if (base + 2 < G) cum[base + 2] = r2;
    if (base + 3 < G) cum[base + 3] = r3;
    if (tid == 255) bsum[blockIdx.x] = excl + s;
}

__global__ void k_scan2(int* __restrict__ bsum, int nb) {
    int t = threadIdx.x;  // 64 threads, nb <= 64
    int v = (t < nb) ? bsum[t] : 0;
#pragma unroll
    for (int off = 1; off < 64; off <<= 1) {
        int u = __shfl_up(v, off, 64);
        if (t >= off) v += u;
    }
    if (t < nb) bsum[t] = v;
}

__global__ void k_gid(const int* __restrict__ ids, const int* __restrict__ cum,
                      const int* __restrict__ bsum, int* __restrict__ gid,
                      int* __restrict__ gstart, int* __restrict__ ngr, int n) {
    int i = blockIdx.x * blockDim.x + threadIdx.x;
    if (i >= n) return;
    int v = ids[i];
    int blk = v >> 10;
    int g = cum[v] + (blk ? bsum[blk - 1] : 0) - 1;
    gid[i] = g;
    if (i == 0 || ids[i - 1] != v) gstart[g] = i;
    if (i == n - 1) { gstart[g + 1] = n; *ngr = g + 1; }
}

// E1 = emb @ W1b^T + b1. 128-row block, LDS-staged, one barrier.
__global__ __launch_bounds__(256, 2) void k_egemm(
    const float* __restrict__ emb, const unsigned short* __restrict__ Wf,
    const float* __restrict__ b1, float* __restrict__ E1, int G) {
    __shared__ __align__(16) float ebuf[16384];   // 64KB: 128 rows f32
    int tid = threadIdx.x, lane = tid & 63, wid = tid >> 6;
    int p = lane & 15, q = lane >> 4;
    int wr = wid >> 1, wc = wid & 1;
    int row0 = blockIdx.x * 128;

    short8 bfr[4][4];
#pragma unroll
    for (int t = 0; t < 4; ++t)
#pragma unroll
        for (int kk = 0; kk < 4; ++kk)
            bfr[t][kk] = *(const short8*)&Wf[(size_t)((wc * 4 + t) * 4 + kk) * 512 + lane * 8];
    float b1v[4];
#pragma unroll
    for (int t = 0; t < 4; ++t) b1v[t] = b1[wc * 64 + t * 16 + p];

    long long maxb = (long long)G * 512 - 16;
#pragma unroll
    for (int k = 0; k < 16; ++k) {
        int doff = k * 4096 + tid * 16;
        int r = doff >> 9;
        long long s = (long long)(row0 + r) * 512 + (long long)((doff & 511) ^ ((r & 7) << 4));
        s = s < maxb ? s : maxb;
        dma16((const char*)emb + s, (char*)ebuf + doff);
    }
    asm volatile("s_waitcnt vmcnt(0)" ::: "memory");
    __builtin_amdgcn_s_barrier();
    __builtin_amdgcn_sched_barrier(0);

    int sw = (p & 7) << 4;
#pragma unroll
    for (int tt = 0; tt < 4; ++tt) {
        int lr = wr * 64 + tt * 16 + p;
        short8 afr[4];
#pragma unroll
        for (int kk = 0; kk < 4; ++kk) {
            int boff = lr * 512 + kk * 128 + q * 32;
            float4 v0 = lds_rd16(ebuf, boff, sw);
            float4 v1 = lds_rd16(ebuf, boff + 16, sw);
            afr[kk] = pack8(v0, v1);
        }
        f32x4 acc[4];
#pragma unroll
        for (int t = 0; t < 4; ++t) acc[t] = f32x4{0.f, 0.f, 0.f, 0.f};
#pragma unroll
        for (int t = 0; t < 4; ++t)
#pragma unroll
            for (int kk = 0; kk < 4; ++kk)
                acc[t] = __builtin_amdgcn_mfma_f32_16x16x32_bf16(afr[kk], bfr[t][kk], acc[t], 0, 0, 0);
#pragma unroll
        for (int t = 0; t < 4; ++t) {
            int colb = wc * 64 + t * 16 + p;
#pragma unroll
            for (int rg = 0; rg < 4; ++rg) {
                int rr = row0 + wr * 64 + tt * 16 + q * 4 + rg;
                if (rr < G) E1[(size_t)rr * 128 + colb] = acc[t][rg] + b1v[t];
            }
        }
    }
}

// x_out = x @ W1a^T + E1[gid]  +  fused group means.
// 64-row block (32KB LDS) -> 4 blocks/CU resident for latency overlap.
// Scan windows = 32 rows; contained groups (same 32-aligned window) -> direct
// imps write (unique writer); crossing -> atomicAdd into zeroed segsum (k_fix).
__global__ __launch_bounds__(256, 4) void k_xgemm(
    const float* __restrict__ x, const unsigned short* __restrict__ Wf,
    const int* __restrict__ gid, const float* __restrict__ E1,
    const int* __restrict__ ngr,
    float* __restrict__ out, unsigned short* __restrict__ imps,
    float* __restrict__ segsum, int N, int nwg) {
    __shared__ __align__(16) float xbuf[8192];   // 32KB: 64 rows f32
    __shared__ int gids[64];
    int tid = threadIdx.x, lane = tid & 63, wid = tid >> 6;
    int p = lane & 15, q = lane >> 4;
    int wr = wid >> 1, wc = wid & 1;
    // bijective XCD swizzle (m204)
    int orig = blockIdx.x;
    int qq = nwg >> 3, rr8 = nwg & 7;
    int xcd = orig & 7, idx = orig >> 3;
    int bid = (xcd < rr8 ? xcd * (qq + 1) : rr8 * (qq + 1) + (xcd - rr8) * qq) + idx;
    int row0 = bid * 64;

    short8 bfr[4][4];
#pragma unroll
    for (int t = 0; t < 4; ++t)
#pragma unroll
        for (int kk = 0; kk < 4; ++kk)
            bfr[t][kk] = *(const short8*)&Wf[(size_t)((wc * 4 + t) * 4 + kk) * 512 + lane * 8];

    int gt[2];
#pragma unroll
    for (int tt = 0; tt < 2; ++tt)
        gt[tt] = gid[min(row0 + wr * 32 + tt * 16 + p, N - 1)];

    // scan geometry + edge loads (issued early, hidden under DMA)
    int c = tid & 127, h = tid >> 7;
    int lo = row0 + h * 32;
    int hi = min(lo + 32, N);
    int gbefore = -1, gafter = -1;
    if (lo > 0 && lo < N) gbefore = gid[lo - 1];
    if (hi < N) gafter = gid[hi];

    long long maxb = (long long)N * 512 - 16;
#pragma unroll
    for (int k = 0; k < 8; ++k) {
        int doff = k * 4096 + tid * 16;
        int r = doff >> 9;
        long long s = (long long)(row0 + r) * 512 + (long long)((doff & 511) ^ ((r & 7) << 4));
        s = s < maxb ? s : maxb;
        dma16((const char*)x + s, (char*)xbuf + doff);
    }
    if (wc == 0) {   // stage this block's gids into LDS (rows wr*32 .. wr*32+31)
#pragma unroll
        for (int tt = 0; tt < 2; ++tt)
            gids[wr * 32 + tt * 16 + p] = gt[tt];
    }
    asm volatile("s_waitcnt vmcnt(0) lgkmcnt(0)" ::: "memory");
    __builtin_amdgcn_s_barrier();
    __builtin_amdgcn_sched_barrier(0);

    int sw = (p & 7) << 4;
#pragma unroll
    for (int tt = 0; tt < 2; ++tt) {
        int lr = wr * 32 + tt * 16 + p;
        short8 afr[4];
#pragma unroll
        for (int kk = 0; kk < 4; ++kk) {
            int boff = lr * 512 + kk * 128 + q * 32;
            float4 v0 = lds_rd16(xbuf, boff, sw);
            float4 v1 = lds_rd16(xbuf, boff + 16, sw);
            afr[kk] = pack8(v0, v1);
        }
        int g4[4];
#pragma unroll
        for (int rg = 0; rg < 4; ++rg) g4[rg] = __shfl(gt[tt], q * 4 + rg);
        float ev[4][4];
#pragma unroll
        for (int t = 0; t < 4; ++t) {
            int colb = wc * 64 + t * 16 + p;
#pragma unroll
            for (int rg = 0; rg < 4; ++rg)
                ev[t][rg] = E1[(size_t)g4[rg] * 128 + colb];
        }
        f32x4 acc[4];
#pragma unroll
        for (int t = 0; t < 4; ++t) acc[t] = f32x4{0.f, 0.f, 0.f, 0.f};
#pragma unroll
        for (int t = 0; t < 4; ++t)
#pragma unroll
            for (int kk = 0; kk < 4; ++kk)
                acc[t] = __builtin_amdgcn_mfma_f32_16x16x32_bf16(afr[kk], bfr[t][kk], acc[t], 0, 0, 0);
#pragma unroll
        for (int t = 0; t < 4; ++t) {
            int colb = wc * 64 + t * 16 + p;
#pragma unroll
            for (int rg = 0; rg < 4; ++rg) {
                int rr = row0 + wr * 32 + tt * 16 + q * 4 + rg;
                if (rr < N) out[(size_t)rr * 128 + colb] = acc[t][rg] + ev[t][rg];
            }
        }
    }

    // ---- fused group means from LDS (batched reads; 32-row window) ----
    if (lo < N) {
        int nwin = hi - lo;                 // 1..32
        int gbase = h * 32;
        int ng = *ngr;
        int gcur = gids[gbase];
        bool open_left = (gcur == gbefore);
        int rs = lo;
        float s = 0.f;
        for (int bb = 0; bb < nwin; bb += 8) {
            float v[8];
            int gn[8];
#pragma unroll
            for (int j = 0; j < 8; ++j) {
                int rr = bb + j; rr = rr < nwin - 1 ? rr : nwin - 1;
                int lrr = gbase + rr;
                v[j] = *(const float*)((const char*)xbuf + lrr * 512 + ((c * 4) ^ ((lrr & 7) << 4)));
                int rn = bb + j + 1; rn = rn < nwin - 1 ? rn : nwin - 1;
                gn[j] = gids[gbase + rn];
            }
#pragma unroll
            for (int j = 0; j < 8; ++j) {
                int r = bb + j;
                if (r < nwin) {
                    s += v[j];
                    bool at_end = (r + 1 >= nwin);
                    int gnext = at_end ? gafter : gn[j];
                    if (at_end || gnext != gcur) {
                        bool open_right = at_end && (gafter == gcur);
                        if (!open_left && !open_right) {
                            if (gcur < ng - 1)
                                imps[(size_t)gcur * 128 + c] = f2bf(s / (float)(lo + r + 1 - rs));
                        } else {
                            atomicAdd(&segsum[(size_t)gcur * 128 + c], s);
                        }
                        s = 0.f; rs = lo + r + 1; gcur = gnext; open_left = false;
                    }
                }
            }
        }
    }
}

// Finish crossing groups (segsum/n) and emb-copy for unwritten tail groups.
// Containment window = 32 rows (must mirror k_xgemm).
__global__ __launch_bounds__(256) void k_fix(
    const float* __restrict__ segsum, const float* __restrict__ emb,
    const int* __restrict__ gstart, const int* __restrict__ ngr,
    unsigned short* __restrict__ imps, int G) {
    int g = blockIdx.x * 4 + (threadIdx.x >> 6);
    int lane = threadIdx.x & 63;
    if (g >= G) return;
    int ng = *ngr;
    float2 m;
    if (g < ng - 1) {
        int a = gstart[g], b = gstart[g + 1];
        if ((a >> 5) == ((b - 1) >> 5)) return;  // contained: imps already written
        float inv = 1.0f / (float)(b - a);
        float2 s = *(const float2*)&segsum[(size_t)g * 128 + lane * 2];
        m.x = s.x * inv; m.y = s.y * inv;
    } else {
        m = *(const float2*)&emb[(size_t)g * 128 + lane * 2];
    }
    unsigned int pk = (unsigned int)f2bf(m.x) | ((unsigned int)f2bf(m.y) << 16);
    ((unsigned int*)imps)[(size_t)g * 64 + lane] = pk;
}

// imputed_out = emb @ W2a^T + imps @ W2b^T + b2. 64-row block, LDS-staged.
__global__ __launch_bounds__(256, 2) void k_igemm(
    const float* __restrict__ emb, const unsigned short* __restrict__ imps,
    const unsigned short* __restrict__ Waf, const unsigned short* __restrict__ Wbf,
    const float* __restrict__ b2, float* __restrict__ out2, int G) {
    __shared__ __align__(16) float ebuf[8192];            // 32KB: 64 rows f32
    __shared__ __align__(16) unsigned short ibuf[8192];   // 16KB: 64 rows bf16
    int tid = threadIdx.x, lane = tid & 63, wid = tid >> 6;
    int p = lane & 15, q = lane >> 4;
    int wr = wid >> 1, wc = wid & 1;
    int row0 = blockIdx.x * 64;

    short8 bfrA[4][4], bfrB[4][4];
#pragma unroll
    for (int t = 0; t < 4; ++t)
#pragma unroll
        for (int kk = 0; kk < 4; ++kk) {
            bfrA[t][kk] = *(const short8*)&Waf[(size_t)((wc * 4 + t) * 4 + kk) * 512 + lane * 8];
            bfrB[t][kk] = *(const short8*)&Wbf[(size_t)((wc * 4 + t) * 4 + kk) * 512 + lane * 8];
        }
    float b2v[4];
#pragma unroll
    for (int t = 0; t < 4; ++t) b2v[t] = b2[wc * 64 + t * 16 + p];

    long long maxe = (long long)G * 512 - 16;
    long long maxi = (long long)G * 256 - 16;
#pragma unroll
    for (int k = 0; k < 8; ++k) {
        int doff = k * 4096 + tid * 16;
        int r = doff >> 9;
        long long s = (long long)(row0 + r) * 512 + (long long)((doff & 511) ^ ((r & 7) << 4));
        s = s < maxe ? s : maxe;
        dma16((const char*)emb + s, (char*)ebuf + doff);
    }
#pragma unroll
    for (int k = 0; k < 4; ++k) {
        int doff = k * 4096 + tid * 16;
        int r = doff >> 8;
        long long s = (long long)(row0 + r) * 256 + (long long)((doff & 255) ^ ((r & 7) << 4));
        s = s < maxi ? s : maxi;
        dma16((const char*)imps + s, (char*)ibuf + doff);
    }
    asm volatile("s_waitcnt vmcnt(0)" ::: "memory");
    __builtin_amdgcn_s_barrier();
    __builtin_amdgcn_sched_barrier(0);

    int sw = (p & 7) << 4;
#pragma unroll
    for (int tt = 0; tt < 2; ++tt) {
        int lr = wr * 32 + tt * 16 + p;
        short8 ae[4], ia[4];
#pragma unroll
        for (int kk = 0; kk < 4; ++kk) {
            int boff = lr * 512 + kk * 128 + q * 32;
            float4 v0 = lds_rd16(ebuf, boff, sw);
            float4 v1 = lds_rd16(ebuf, boff + 16, sw);
            ae[kk] = pack8(v0, v1);
            int boff2 = lr * 256 + ((kk * 64 + q * 16) ^ sw);
            ia[kk] = *(const short8*)((const char*)ibuf + boff2);
        }
        f32x4 acc[4];
#pragma unroll
        for (int t = 0; t < 4; ++t) acc[t] = f32x4{0.f, 0.f, 0.f, 0.f};
#pragma unroll
        for (int kk = 0; kk < 4; ++kk)
#pragma unroll
            for (int t = 0; t < 4; ++t) {
                acc[t] = __builtin_amdgcn_mfma_f32_16x16x32_bf16(ae[kk], bfrA[t][kk], acc[t], 0, 0, 0);
                acc[t] = __builtin_amdgcn_mfma_f32_16x16x32_bf16(ia[kk], bfrB[t][kk], acc[t], 0, 0, 0);
            }
#pragma unroll
        for (int t = 0; t < 4; ++t) {
            int colb = wc * 64 + t * 16 + p;
#pragma unroll
            for (int rg = 0; rg < 4; ++rg) {
                int rr = row0 + wr * 32 + tt * 16 + q * 4 + rg;
                if (rr < G) out2[(size_t)rr * 128 + colb] = acc[t][rg] + b2v[t];
            }
        }
    }
}

extern "C" void kernel_launch(void* const* d_in, const int* in_sizes, int n_in,
                              void* d_out, int out_size, void* d_ws, size_t ws_size,
                              hipStream_t stream) {
    const float* x   = (const float*)d_in[0];
    const float* emb = (const float*)d_in[1];
    const float* W1  = (const float*)d_in[2];
    const float* b1  = (const float*)d_in[3];
    const float* W2  = (const float*)d_in[4];
    const float* b2  = (const float*)d_in[5];
    const int*   ids = (const int*)d_in[6];
    const int H = 128;
    const int N = in_sizes[6];
    const int G = in_sizes[1] / H;

    float* out  = (float*)d_out;
    float* out2 = out + (size_t)N * H;
    float* E1   = out2;  // E1 scratch lives in imputed_out region (overwritten by k_igemm last)

    char* ws = (char*)d_ws;
    size_t off = 0;
    float* segsum = (float*)(ws + off); off += (size_t)G * H * 4;
    int*   cum    = (int*)(ws + off);   off += (size_t)G * 4;
    size_t zbytes = off;                              // zero region: segsum + cum
    off = (off + 255) & ~(size_t)255;
    int* bsum   = (int*)(ws + off); off += 64 * 4;          off = (off + 255) & ~(size_t)255;
    int* gid    = (int*)(ws + off); off += (size_t)N * 4;   off = (off + 255) & ~(size_t)255;
    int* gstart = (int*)(ws + off); off += (size_t)(G + 1) * 4; off = (off + 255) & ~(size_t)255;
    int* ngr    = (int*)(ws + off); off += 256;
    unsigned short* W1af = (unsigned short*)(ws + off); off += (size_t)H * H * 2;
    unsigned short* W1bf = (unsigned short*)(ws + off); off += (size_t)H * H * 2;
    unsigned short* W2af = (unsigned short*)(ws + off); off += (size_t)H * H * 2;
    unsigned short* W2bf = (unsigned short*)(ws + off); off += (size_t)H * H * 2;
    unsigned short* imps = (unsigned short*)(ws + off); off += (size_t)G * H * 2;

    int n16 = (int)((zbytes + 15) / 16);
    int nb = (G + 1023) >> 10;
    int nwgX = (N + 63) >> 6;
    int nwgE = (G + 127) >> 7;
    int nwgI = (G + 63) >> 6;
    k_zero<<<(n16 + 255) / 256, 256, 0, stream>>>((uint4*)ws, n16);
    k_convw<<<32, 256, 0, stream>>>(W1, W2, W1af, W1bf, W2af, W2bf);
    k_mark<<<(N + 255) / 256, 256, 0, stream>>>(ids, cum, N);
    k_scan1<<<nb, 256, 0, stream>>>(cum, bsum, G);
    k_scan2<<<1, 64, 0, stream>>>(bsum, nb);
    k_gid<<<(N + 255) / 256, 256, 0, stream>>>(ids, cum, bsum, gid, gstart, ngr, N);
    k_egemm<<<nwgE, 256, 0, stream>>>(emb, W1bf, b1, E1, G);
    k_xgemm<<<nwgX, 256, 0, stream>>>(x, W1af, gid, E1, ngr, out, imps, segsum, N, nwgX);
    k_fix<<<(G + 3) / 4, 256, 0, stream>>>(segsum, emb, gstart, ngr, imps, G);
    k_igemm<<<nwgI, 256, 0, stream>>>(emb, imps, W2af, W2bf, b2, out2, G);
}